// Round 1
// baseline (306.266 us; speedup 1.0000x reference)
//
#include <hip/hip_runtime.h>
#include <cstdint>

// ---------------------------------------------------------------------------
// RotationScan: theta/retain/inp GEMM -> chunked complex scan -> out GEMM -> LN
// B=4 T=4096 D=1024 SD=512 CHUNK=32
// ---------------------------------------------------------------------------

typedef __bf16 bf16x8 __attribute__((ext_vector_type(8)));
typedef float  f32x4  __attribute__((ext_vector_type(4)));

#define AS1 __attribute__((address_space(1)))
#define AS3 __attribute__((address_space(3)))

__device__ __forceinline__ void gload16(const void* g, void* l) {
  __builtin_amdgcn_global_load_lds((const AS1 void*)g, (AS3 void*)l, 16, 0, 0);
}

__device__ __forceinline__ ushort f2bf(float f) {
  union { float f; uint32_t u; } v; v.f = f;
  uint32_t u = v.u;
  uint32_t r = u + 0x7FFFu + ((u >> 16) & 1u);   // RNE
  return (ushort)(r >> 16);
}

// ---------------------------------------------------------------------------
// Transpose + f32->bf16 convert:  dst[(row_off + c)*R + r] = bf16(src[r*C + c])
// ---------------------------------------------------------------------------
__global__ __launch_bounds__(256) void tconv(const float* __restrict__ src, int R, int C,
                                             ushort* __restrict__ dst, int row_off) {
  __shared__ float tile[32][33];
  int tx = threadIdx.x, ty = threadIdx.y;
  int rb = blockIdx.y * 32, cb = blockIdx.x * 32;
#pragma unroll
  for (int yy = 0; yy < 4; ++yy) {
    int r = rb + ty + yy * 8;
    tile[ty + yy * 8][tx] = src[(size_t)r * C + cb + tx];
  }
  __syncthreads();
#pragma unroll
  for (int yy = 0; yy < 4; ++yy) {
    int c = cb + ty + yy * 8;
    dst[(size_t)(row_off + c) * R + rb + tx] = f2bf(tile[tx][ty + yy * 8]);
  }
}

__global__ __launch_bounds__(256) void pack_bias(const float* __restrict__ bt,
                                                 const float* __restrict__ br,
                                                 const float* __restrict__ bi,
                                                 float* __restrict__ bcat) {
  int i = blockIdx.x * 256 + threadIdx.x;          // 0..2047
  bcat[i] = (i < 512) ? bt[i] : (i < 1024 ? br[i - 512] : bi[i - 1024]);
}

__global__ __launch_bounds__(256) void xconv(const float4* __restrict__ src,
                                             ushort* __restrict__ dst, int n4) {
  int i = blockIdx.x * 256 + threadIdx.x;
  if (i < n4) {
    float4 v = src[i];
    ushort4 o;
    o.x = f2bf(v.x); o.y = f2bf(v.y); o.z = f2bf(v.z); o.w = f2bf(v.w);
    *(ushort4*)(dst + (size_t)i * 4) = o;
  }
}

// ---------------------------------------------------------------------------
// bf16 GEMM: C[M,N](f32) = A[M,K](bf16) @ Bt[N,K](bf16)^T + bias[N] (+ addm[M,N])
// 128x128 tile, BK=64, 4 waves 2x2, XOR-swizzled LDS (st-8x16B), global_load_lds.
// ---------------------------------------------------------------------------
__global__ __launch_bounds__(256) void gemm_bf16(const ushort* __restrict__ A,
                                                 const ushort* __restrict__ Bt,
                                                 float* __restrict__ C,
                                                 const float* __restrict__ bias,
                                                 const float* __restrict__ addm,
                                                 int M, int N, int K) {
  __shared__ alignas(16) ushort Atile[128 * 64];
  __shared__ alignas(16) ushort Btile[128 * 64];
  const int t = threadIdx.x;
  const int l = t & 63;
  const int w = t >> 6;
  const int wr = w >> 1, wc = w & 1;
  const int bm = blockIdx.y, bn = blockIdx.x;

  f32x4 acc[4][4] = {};

  const int m_local0 = t >> 3;       // row covered by this thread within a pass
  const int jslot = t & 7;           // physical 16B slot within the 128B row
  const size_t a_row0 = (size_t)bm * 128 * K;
  const size_t b_row0 = (size_t)bn * 128 * K;

  const int r  = l & 15;
  const int kq = l >> 4;
  const int nkt = K >> 6;

  for (int kt = 0; kt < nkt; ++kt) {
    const int kcol = kt * 64;
    // ---- stage A,B tile (16KB each) with pre-swizzled global source ----
#pragma unroll
    for (int p = 0; p < 4; ++p) {
      int ml = p * 32 + m_local0;
      int s = jslot ^ (ml & 7);                       // logical slot to fetch
      const ushort* ga = A + a_row0 + (size_t)ml * K + kcol + s * 8;
      const ushort* gb = Bt + b_row0 + (size_t)ml * K + kcol + s * 8;
      ushort* la = Atile + (size_t)(p * 256 + w * 64) * 8;   // wave-uniform base
      ushort* lb = Btile + (size_t)(p * 256 + w * 64) * 8;
      gload16(ga, la);
      gload16(gb, lb);
    }
    __syncthreads();   // drains vmcnt then barriers
    // ---- compute: 2 K-steps of 32, 16 MFMA each ----
#pragma unroll
    for (int ks = 0; ks < 2; ++ks) {
      int sA = ks * 4 + kq;                // logical slot for this lane's k-range
      int j = sA ^ (r & 7);                // physical slot after swizzle
      bf16x8 af[4], bfr[4];
#pragma unroll
      for (int i = 0; i < 4; ++i) {
        int m = wr * 64 + i * 16 + r;
        af[i] = *(const bf16x8*)(Atile + (size_t)m * 64 + j * 8);
        int n = wc * 64 + i * 16 + r;
        bfr[i] = *(const bf16x8*)(Btile + (size_t)n * 64 + j * 8);
      }
#pragma unroll
      for (int i = 0; i < 4; ++i)
#pragma unroll
        for (int jn = 0; jn < 4; ++jn)
          acc[i][jn] = __builtin_amdgcn_mfma_f32_16x16x32_bf16(af[i], bfr[jn], acc[i][jn], 0, 0, 0);
    }
    __syncthreads();
  }

  // ---- epilogue: C/D layout col=lane&15, row=(lane>>4)*4+q ----
  const int q4 = (l >> 4) * 4;
#pragma unroll
  for (int i = 0; i < 4; ++i) {
#pragma unroll
    for (int jn = 0; jn < 4; ++jn) {
      int gcol = bn * 128 + wc * 64 + jn * 16 + r;
      float bv = bias ? bias[gcol] : 0.f;
#pragma unroll
      for (int q = 0; q < 4; ++q) {
        int grow = bm * 128 + wr * 64 + i * 16 + q4 + q;
        float v = acc[i][jn][q] + bv;
        if (addm) v += addm[(size_t)grow * N + gcol];
        C[(size_t)grow * N + gcol] = v;
      }
    }
  }
}

// ---------------------------------------------------------------------------
// Scan kernels. lin[row, 2048]: [theta | retain_logit | inp_r | inp_i]
// Replicates reference chunk math exactly (incl. 1e-6 / 1e-8 clips).
// ---------------------------------------------------------------------------
__global__ __launch_bounds__(256) void scan_k1(const float* __restrict__ lin,
                                               float4* __restrict__ agg) {
  int bd = blockIdx.x * 256 + threadIdx.x;    // 0..2047  (b*512 + d)
  int c  = blockIdx.y;                         // 0..127
  int b  = bd >> 9, d = bd & 511;
  const float* base = lin + ((size_t)b * 4096 + (size_t)c * 32) * 2048;
  float clm = 0.f, cth = 0.f, cbr = 0.f, cbi = 0.f;
  float cm = 1.f, cs = 1.f, sn = 0.f;
  for (int t = 0; t < 32; ++t) {
    const float* row = base + (size_t)t * 2048;
    float th = row[d];
    float z  = row[512 + d];
    float ir = row[1024 + d];
    float ii = row[1536 + d];
    float rt = 1.f / (1.f + expf(-z));
    clm += logf(fmaxf(rt, 1e-6f));
    cth += th;
    cm = expf(clm);
    float s_, c_;
    sincosf(cth, &s_, &c_);
    float im = 1.f / fmaxf(cm, 1e-8f);
    float invr = im * c_, invi = -im * s_;
    float drive = 1.f - rt;
    float br_ = drive * ir, bi_ = drive * ii;
    cbr += invr * br_ - invi * bi_;
    cbi += invr * bi_ + invi * br_;
    cs = c_; sn = s_;
  }
  agg[(size_t)c * 2048 + bd] = make_float4(cm * cs, cm * sn, cbr, cbi);
}

__global__ __launch_bounds__(256) void scan_k2(const float4* __restrict__ agg,
                                               float2* __restrict__ h0) {
  int bd = blockIdx.x * 256 + threadIdx.x;    // 2048 threads
  float hr = 0.f, hi = 0.f;
  for (int cg = 0; cg < 16; ++cg) {
    float4 a[8];
#pragma unroll
    for (int u = 0; u < 8; ++u) a[u] = agg[(size_t)(cg * 8 + u) * 2048 + bd];
#pragma unroll
    for (int u = 0; u < 8; ++u) {
      h0[(size_t)(cg * 8 + u) * 2048 + bd] = make_float2(hr, hi);
      float tr = hr + a[u].z, ti = hi + a[u].w;
      hr = a[u].x * tr - a[u].y * ti;
      hi = a[u].x * ti + a[u].y * tr;
    }
  }
}

__global__ __launch_bounds__(256) void scan_k3(const float* __restrict__ lin,
                                               const float2* __restrict__ h0,
                                               ushort* __restrict__ outb) {
  int bd = blockIdx.x * 256 + threadIdx.x;
  int c  = blockIdx.y;
  int b  = bd >> 9, d = bd & 511;
  const float* base = lin + ((size_t)b * 4096 + (size_t)c * 32) * 2048;
  float2 h = h0[(size_t)c * 2048 + bd];
  float clm = 0.f, cth = 0.f, cbr = 0.f, cbi = 0.f;
  for (int t = 0; t < 32; ++t) {
    const float* row = base + (size_t)t * 2048;
    float th = row[d];
    float z  = row[512 + d];
    float ir = row[1024 + d];
    float ii = row[1536 + d];
    float rt = 1.f / (1.f + expf(-z));
    clm += logf(fmaxf(rt, 1e-6f));
    cth += th;
    float cm = expf(clm);
    float s_, c_;
    sincosf(cth, &s_, &c_);
    float im = 1.f / fmaxf(cm, 1e-8f);
    float invr = im * c_, invi = -im * s_;
    float drive = 1.f - rt;
    float br_ = drive * ir, bi_ = drive * ii;
    cbr += invr * br_ - invi * bi_;
    cbi += invr * bi_ + invi * br_;
    float ar = cm * c_, ai = cm * s_;
    float tr = h.x + cbr, ti = h.y + cbi;
    float orr = ar * tr - ai * ti;
    float oii = ar * ti + ai * tr;
    size_t rowo = ((size_t)b * 4096 + (size_t)c * 32 + t) * 1024;
    outb[rowo + d] = f2bf(orr);
    outb[rowo + 512 + d] = f2bf(oii);
  }
}

// ---------------------------------------------------------------------------
// LayerNorm over D=1024, one block per row.
// ---------------------------------------------------------------------------
__global__ __launch_bounds__(256) void ln_k(const float* __restrict__ y,
                                            const float* __restrict__ gamma,
                                            const float* __restrict__ beta,
                                            float* __restrict__ out) {
  int row = blockIdx.x;
  const float4* yr = (const float4*)(y + (size_t)row * 1024);
  float4 v = yr[threadIdx.x];
  float s  = v.x + v.y + v.z + v.w;
  float s2 = v.x * v.x + v.y * v.y + v.z * v.z + v.w * v.w;
#pragma unroll
  for (int off = 32; off > 0; off >>= 1) {
    s  += __shfl_down(s, off);
    s2 += __shfl_down(s2, off);
  }
  __shared__ float red[8];
  __shared__ float mv[2];
  int l = threadIdx.x & 63, w = threadIdx.x >> 6;
  if (l == 0) { red[w] = s; red[4 + w] = s2; }
  __syncthreads();
  if (threadIdx.x == 0) {
    float ts = red[0] + red[1] + red[2] + red[3];
    float t2 = red[4] + red[5] + red[6] + red[7];
    float mu = ts * (1.f / 1024.f);
    float var = t2 * (1.f / 1024.f) - mu * mu;
    mv[0] = mu;
    mv[1] = 1.f / sqrtf(var + 1e-5f);
  }
  __syncthreads();
  float mu = mv[0], rstd = mv[1];
  const float4* g4 = (const float4*)gamma;
  const float4* b4 = (const float4*)beta;
  float4 gv = g4[threadIdx.x], bv = b4[threadIdx.x];
  float4 o;
  o.x = (v.x - mu) * rstd * gv.x + bv.x;
  o.y = (v.y - mu) * rstd * gv.y + bv.y;
  o.z = (v.z - mu) * rstd * gv.z + bv.z;
  o.w = (v.w - mu) * rstd * gv.w + bv.w;
  ((float4*)(out + (size_t)row * 1024))[threadIdx.x] = o;
}

// ---------------------------------------------------------------------------
extern "C" void kernel_launch(void* const* d_in, const int* in_sizes, int n_in,
                              void* d_out, int out_size, void* d_ws, size_t ws_size,
                              hipStream_t stream) {
  (void)in_sizes; (void)n_in; (void)out_size; (void)ws_size;
  const float* x  = (const float*)d_in[0];
  const float* Wt = (const float*)d_in[1];
  const float* bt = (const float*)d_in[2];
  const float* Wr = (const float*)d_in[3];
  const float* br = (const float*)d_in[4];
  const float* Wi = (const float*)d_in[5];
  const float* bi = (const float*)d_in[6];
  const float* Wo = (const float*)d_in[7];
  const float* bo = (const float*)d_in[8];
  const float* gamma = (const float*)d_in[9];
  const float* beta  = (const float*)d_in[10];

  char* ws = (char*)d_ws;
  ushort* wcat_t = (ushort*)(ws);                     //  4 MiB: [2048][1024] bf16
  ushort* wo_t   = (ushort*)(ws + ((size_t)4  << 20)); //  2 MiB: [1024][1024] bf16
  float*  bcat   = (float*) (ws + ((size_t)6  << 20)); //  8 KiB
  float4* agg    = (float4*)(ws + ((size_t)8  << 20)); //  4 MiB: [128][2048]
  float2* h0     = (float2*)(ws + ((size_t)12 << 20)); //  2 MiB: [128][2048]
  ushort* xb     = (ushort*)(ws + ((size_t)16 << 20)); // 32 MiB: x bf16, later out bf16
  float*  lin    = (float*) (ws + ((size_t)48 << 20)); // 128 MiB: lin, later y (first 64)

  // weight prep
  tconv<<<dim3(512 / 32, 1024 / 32), dim3(32, 8), 0, stream>>>(Wt, 1024, 512, wcat_t, 0);
  tconv<<<dim3(512 / 32, 1024 / 32), dim3(32, 8), 0, stream>>>(Wr, 1024, 512, wcat_t, 512);
  tconv<<<dim3(1024 / 32, 1024 / 32), dim3(32, 8), 0, stream>>>(Wi, 1024, 1024, wcat_t, 1024);
  tconv<<<dim3(1024 / 32, 1024 / 32), dim3(32, 8), 0, stream>>>(Wo, 1024, 1024, wo_t, 0);
  pack_bias<<<8, 256, 0, stream>>>(bt, br, bi, bcat);
  xconv<<<16384, 256, 0, stream>>>((const float4*)x, xb, 4194304);

  // lin = x @ [Wt|Wr|Wi] + [bt|br|bi]
  gemm_bf16<<<dim3(2048 / 128, 16384 / 128), 256, 0, stream>>>(
      xb, wcat_t, lin, bcat, nullptr, 16384, 2048, 1024);

  // chunked complex scan
  scan_k1<<<dim3(8, 128), 256, 0, stream>>>(lin, agg);
  scan_k2<<<8, 256, 0, stream>>>(agg, h0);
  scan_k3<<<dim3(8, 128), 256, 0, stream>>>(lin, h0, xb /* -> out bf16, x dead */);

  // y = x + out @ Wo + bo   (y overwrites lin's first 64 MiB)
  gemm_bf16<<<dim3(1024 / 128, 16384 / 128), 256, 0, stream>>>(
      xb, wo_t, lin, bo, x, 16384, 1024, 1024);

  // layernorm -> d_out
  ln_k<<<16384, 256, 0, stream>>>(lin, gamma, beta, (float*)d_out);
}

// Round 2
// 293.681 us; speedup vs baseline: 1.0429x; 1.0429x over previous
//
#include <hip/hip_runtime.h>
#include <cstdint>

// ---------------------------------------------------------------------------
// RotationScan: theta/retain/inp GEMM -> chunked complex scan -> out GEMM -> LN
// B=4 T=4096 D=1024 SD=512 CHUNK=32
// ---------------------------------------------------------------------------

typedef __bf16 bf16x8 __attribute__((ext_vector_type(8)));
typedef float  f32x4  __attribute__((ext_vector_type(4)));

#define AS1 __attribute__((address_space(1)))
#define AS3 __attribute__((address_space(3)))

__device__ __forceinline__ void gload16(const void* g, void* l) {
  __builtin_amdgcn_global_load_lds((const AS1 void*)g, (AS3 void*)l, 16, 0, 0);
}

__device__ __forceinline__ ushort f2bf(float f) {
  union { float f; uint32_t u; } v; v.f = f;
  uint32_t u = v.u;
  uint32_t r = u + 0x7FFFu + ((u >> 16) & 1u);   // RNE
  return (ushort)(r >> 16);
}

// ---------------------------------------------------------------------------
// Transpose + f32->bf16 convert:  dst[(row_off + c)*R + r] = bf16(src[r*C + c])
// ---------------------------------------------------------------------------
__global__ __launch_bounds__(256) void tconv(const float* __restrict__ src, int R, int C,
                                             ushort* __restrict__ dst, int row_off) {
  __shared__ float tile[32][33];
  int tx = threadIdx.x, ty = threadIdx.y;
  int rb = blockIdx.y * 32, cb = blockIdx.x * 32;
#pragma unroll
  for (int yy = 0; yy < 4; ++yy) {
    int r = rb + ty + yy * 8;
    tile[ty + yy * 8][tx] = src[(size_t)r * C + cb + tx];
  }
  __syncthreads();
#pragma unroll
  for (int yy = 0; yy < 4; ++yy) {
    int c = cb + ty + yy * 8;
    dst[(size_t)(row_off + c) * R + rb + tx] = f2bf(tile[tx][ty + yy * 8]);
  }
}

__global__ __launch_bounds__(256) void pack_bias(const float* __restrict__ bt,
                                                 const float* __restrict__ br,
                                                 const float* __restrict__ bi,
                                                 float* __restrict__ bcat) {
  int i = blockIdx.x * 256 + threadIdx.x;          // 0..2047
  bcat[i] = (i < 512) ? bt[i] : (i < 1024 ? br[i - 512] : bi[i - 1024]);
}

__global__ __launch_bounds__(256) void xconv(const float4* __restrict__ src,
                                             ushort* __restrict__ dst, int n4) {
  int i = blockIdx.x * 256 + threadIdx.x;
  if (i < n4) {
    float4 v = src[i];
    ushort4 o;
    o.x = f2bf(v.x); o.y = f2bf(v.y); o.z = f2bf(v.z); o.w = f2bf(v.w);
    *(ushort4*)(dst + (size_t)i * 4) = o;
  }
}

// ---------------------------------------------------------------------------
// 256x256 tile, BK=64, 8 waves (2Mx4N), phase-split schedule with raw
// s_barrier + per-K-tile vmcnt(0), setprio around MFMA clusters, XCD swizzle.
// C[M,N](f32) = A[M,K](bf16) @ Bt[N,K](bf16)^T + bias[N] (+ addm[M,N])
// LDS: A 2x32KB + B 2x32KB = 128 KiB (double-buffered per K-tile).
// Swizzle: physical 16B slot = logical ^ (row & 7)  (verified conflict-free r1).
// ---------------------------------------------------------------------------
__global__ __launch_bounds__(512, 2) void gemm256(const ushort* __restrict__ A,
                                                  const ushort* __restrict__ Bt,
                                                  float* __restrict__ C,
                                                  const float* __restrict__ bias,
                                                  const float* __restrict__ addm,
                                                  int M, int N, int K, int nbn) {
  __shared__ alignas(16) ushort As[2][256 * 64];
  __shared__ alignas(16) ushort Bs[2][256 * 64];

  // XCD-bijective block swizzle (gridDim.x % 8 == 0 guaranteed by launch)
  const int cpx = gridDim.x >> 3;
  const int orig = blockIdx.x;
  const int wg = (orig & 7) * cpx + (orig >> 3);
  const int bm = wg / nbn, bn = wg % nbn;

  const int t = threadIdx.x;
  const int l = t & 63, w = t >> 6;
  const int wm = w >> 2, wn = w & 3;            // wave grid 2(M) x 4(N)
  const int r = l & 15, kq = l >> 4;

  const size_t a0 = (size_t)bm * 256 * K;
  const size_t b0 = (size_t)bn * 256 * K;

  // staging map: pass u covers rows u*64 + (t>>3); 16B slot (t&7)^(row&7)
  const int srow = t >> 3;
  const int sslot = (t & 7) ^ (srow & 7);
  const ushort* gA = A + a0 + (size_t)srow * K + sslot * 8;
  const ushort* gB = Bt + b0 + (size_t)srow * K + sslot * 8;

  f32x4 acc[8][4] = {};

  const int NKT = K >> 6;

#define STAGE(buf, kt)                                                         \
  do {                                                                         \
    const int kcol = (kt) * 64;                                                \
    char* la = (char*)As[buf] + w * 1024;                                      \
    char* lb = (char*)Bs[buf] + w * 1024;                                      \
    _Pragma("unroll")                                                          \
    for (int u = 0; u < 4; ++u) {                                              \
      gload16(gA + (size_t)(u * 64) * K + kcol, la + u * 8192);                \
      gload16(gB + (size_t)(u * 64) * K + kcol, lb + u * 8192);                \
    }                                                                          \
  } while (0)

  // prologue: tile 0 resident
  STAGE(0, 0);
  asm volatile("s_waitcnt vmcnt(0)" ::: "memory");
  __builtin_amdgcn_s_barrier();

  for (int kt = 0; kt < NKT; ++kt) {
    const int cur = kt & 1, nxt = cur ^ 1;
    // issue ALL of next tile's loads up front: ~1 K-tile of MFMA cover
    if (kt + 1 < NKT) STAGE(nxt, kt + 1);

    // B fragments for the whole K-tile (reused by all 4 phases)
    bf16x8 bF[4][2];
#pragma unroll
    for (int jn = 0; jn < 4; ++jn) {
      const int row = wn * 64 + jn * 16 + r;
#pragma unroll
      for (int ks = 0; ks < 2; ++ks) {
        const int j = (ks * 4 + kq) ^ (r & 7);
        bF[jn][ks] = *(const bf16x8*)&Bs[cur][row * 64 + j * 8];
      }
    }

#pragma unroll
    for (int ph = 0; ph < 4; ++ph) {
      bf16x8 aF[2][2];
#pragma unroll
      for (int ii = 0; ii < 2; ++ii) {
        const int row = wm * 128 + (ph * 2 + ii) * 16 + r;
#pragma unroll
        for (int ks = 0; ks < 2; ++ks) {
          const int j = (ks * 4 + kq) ^ (r & 7);
          aF[ii][ks] = *(const bf16x8*)&As[cur][row * 64 + j * 8];
        }
      }
      __builtin_amdgcn_s_barrier();          // phase lockstep (no vmcnt drain)
      __builtin_amdgcn_s_setprio(1);
#pragma unroll
      for (int ii = 0; ii < 2; ++ii)
#pragma unroll
        for (int jn = 0; jn < 4; ++jn)
#pragma unroll
          for (int ks = 0; ks < 2; ++ks)
            acc[ph * 2 + ii][jn] = __builtin_amdgcn_mfma_f32_16x16x32_bf16(
                aF[ii][ks], bF[jn][ks], acc[ph * 2 + ii][jn], 0, 0, 0);
      __builtin_amdgcn_s_setprio(0);
      __builtin_amdgcn_s_barrier();
    }

    // K-tile boundary: own loads landed -> barrier makes ALL waves' loads visible
    asm volatile("s_waitcnt vmcnt(0)" ::: "memory");
    __builtin_amdgcn_s_barrier();
  }
#undef STAGE

  // epilogue: C/D layout col=lane&15, row=(lane>>4)*4+q (verified r1)
  const int q4 = (l >> 4) * 4;
#pragma unroll
  for (int i = 0; i < 8; ++i) {
#pragma unroll
    for (int jn = 0; jn < 4; ++jn) {
      const int gcol = bn * 256 + wn * 64 + jn * 16 + r;
      const float bv = bias ? bias[gcol] : 0.f;
#pragma unroll
      for (int q = 0; q < 4; ++q) {
        const int grow = bm * 256 + wm * 128 + i * 16 + q4 + q;
        float v = acc[i][jn][q] + bv;
        if (addm) v += addm[(size_t)grow * N + gcol];
        C[(size_t)grow * N + gcol] = v;
      }
    }
  }
}

// ---------------------------------------------------------------------------
// Scan kernels. lin[row, 2048]: [theta | retain_logit | inp_r | inp_i]
// Replicates reference chunk math exactly (incl. 1e-6 / 1e-8 clips).
// ---------------------------------------------------------------------------
__global__ __launch_bounds__(256) void scan_k1(const float* __restrict__ lin,
                                               float4* __restrict__ agg) {
  int bd = blockIdx.x * 256 + threadIdx.x;    // 0..2047  (b*512 + d)
  int c  = blockIdx.y;                         // 0..127
  int b  = bd >> 9, d = bd & 511;
  const float* base = lin + ((size_t)b * 4096 + (size_t)c * 32) * 2048;
  float clm = 0.f, cth = 0.f, cbr = 0.f, cbi = 0.f;
  float cm = 1.f, cs = 1.f, sn = 0.f;
  for (int t = 0; t < 32; ++t) {
    const float* row = base + (size_t)t * 2048;
    float th = row[d];
    float z  = row[512 + d];
    float ir = row[1024 + d];
    float ii = row[1536 + d];
    float rt = 1.f / (1.f + expf(-z));
    clm += logf(fmaxf(rt, 1e-6f));
    cth += th;
    cm = expf(clm);
    float s_, c_;
    sincosf(cth, &s_, &c_);
    float im = 1.f / fmaxf(cm, 1e-8f);
    float invr = im * c_, invi = -im * s_;
    float drive = 1.f - rt;
    float br_ = drive * ir, bi_ = drive * ii;
    cbr += invr * br_ - invi * bi_;
    cbi += invr * bi_ + invi * br_;
    cs = c_; sn = s_;
  }
  agg[(size_t)c * 2048 + bd] = make_float4(cm * cs, cm * sn, cbr, cbi);
}

__global__ __launch_bounds__(256) void scan_k2(const float4* __restrict__ agg,
                                               float2* __restrict__ h0) {
  int bd = blockIdx.x * 256 + threadIdx.x;    // 2048 threads
  float hr = 0.f, hi = 0.f;
  for (int cg = 0; cg < 16; ++cg) {
    float4 a[8];
#pragma unroll
    for (int u = 0; u < 8; ++u) a[u] = agg[(size_t)(cg * 8 + u) * 2048 + bd];
#pragma unroll
    for (int u = 0; u < 8; ++u) {
      h0[(size_t)(cg * 8 + u) * 2048 + bd] = make_float2(hr, hi);
      float tr = hr + a[u].z, ti = hi + a[u].w;
      hr = a[u].x * tr - a[u].y * ti;
      hi = a[u].x * ti + a[u].y * tr;
    }
  }
}

__global__ __launch_bounds__(256) void scan_k3(const float* __restrict__ lin,
                                               const float2* __restrict__ h0,
                                               ushort* __restrict__ outb) {
  int bd = blockIdx.x * 256 + threadIdx.x;
  int c  = blockIdx.y;
  int b  = bd >> 9, d = bd & 511;
  const float* base = lin + ((size_t)b * 4096 + (size_t)c * 32) * 2048;
  float2 h = h0[(size_t)c * 2048 + bd];
  float clm = 0.f, cth = 0.f, cbr = 0.f, cbi = 0.f;
  for (int t = 0; t < 32; ++t) {
    const float* row = base + (size_t)t * 2048;
    float th = row[d];
    float z  = row[512 + d];
    float ir = row[1024 + d];
    float ii = row[1536 + d];
    float rt = 1.f / (1.f + expf(-z));
    clm += logf(fmaxf(rt, 1e-6f));
    cth += th;
    float cm = expf(clm);
    float s_, c_;
    sincosf(cth, &s_, &c_);
    float im = 1.f / fmaxf(cm, 1e-8f);
    float invr = im * c_, invi = -im * s_;
    float drive = 1.f - rt;
    float br_ = drive * ir, bi_ = drive * ii;
    cbr += invr * br_ - invi * bi_;
    cbi += invr * bi_ + invi * br_;
    float ar = cm * c_, ai = cm * s_;
    float tr = h.x + cbr, ti = h.y + cbi;
    float orr = ar * tr - ai * ti;
    float oii = ar * ti + ai * tr;
    size_t rowo = ((size_t)b * 4096 + (size_t)c * 32 + t) * 1024;
    outb[rowo + d] = f2bf(orr);
    outb[rowo + 512 + d] = f2bf(oii);
  }
}

// ---------------------------------------------------------------------------
// LayerNorm over D=1024, one block per row.
// ---------------------------------------------------------------------------
__global__ __launch_bounds__(256) void ln_k(const float* __restrict__ y,
                                            const float* __restrict__ gamma,
                                            const float* __restrict__ beta,
                                            float* __restrict__ out) {
  int row = blockIdx.x;
  const float4* yr = (const float4*)(y + (size_t)row * 1024);
  float4 v = yr[threadIdx.x];
  float s  = v.x + v.y + v.z + v.w;
  float s2 = v.x * v.x + v.y * v.y + v.z * v.z + v.w * v.w;
#pragma unroll
  for (int off = 32; off > 0; off >>= 1) {
    s  += __shfl_down(s, off);
    s2 += __shfl_down(s2, off);
  }
  __shared__ float red[8];
  __shared__ float mv[2];
  int l = threadIdx.x & 63, w = threadIdx.x >> 6;
  if (l == 0) { red[w] = s; red[4 + w] = s2; }
  __syncthreads();
  if (threadIdx.x == 0) {
    float ts = red[0] + red[1] + red[2] + red[3];
    float t2 = red[4] + red[5] + red[6] + red[7];
    float mu = ts * (1.f / 1024.f);
    float var = t2 * (1.f / 1024.f) - mu * mu;
    mv[0] = mu;
    mv[1] = 1.f / sqrtf(var + 1e-5f);
  }
  __syncthreads();
  float mu = mv[0], rstd = mv[1];
  const float4* g4 = (const float4*)gamma;
  const float4* b4 = (const float4*)beta;
  float4 gv = g4[threadIdx.x], bv = b4[threadIdx.x];
  float4 o;
  o.x = (v.x - mu) * rstd * gv.x + bv.x;
  o.y = (v.y - mu) * rstd * gv.y + bv.y;
  o.z = (v.z - mu) * rstd * gv.z + bv.z;
  o.w = (v.w - mu) * rstd * gv.w + bv.w;
  ((float4*)(out + (size_t)row * 1024))[threadIdx.x] = o;
}

// ---------------------------------------------------------------------------
extern "C" void kernel_launch(void* const* d_in, const int* in_sizes, int n_in,
                              void* d_out, int out_size, void* d_ws, size_t ws_size,
                              hipStream_t stream) {
  (void)in_sizes; (void)n_in; (void)out_size; (void)ws_size;
  const float* x  = (const float*)d_in[0];
  const float* Wt = (const float*)d_in[1];
  const float* bt = (const float*)d_in[2];
  const float* Wr = (const float*)d_in[3];
  const float* br = (const float*)d_in[4];
  const float* Wi = (const float*)d_in[5];
  const float* bi = (const float*)d_in[6];
  const float* Wo = (const float*)d_in[7];
  const float* bo = (const float*)d_in[8];
  const float* gamma = (const float*)d_in[9];
  const float* beta  = (const float*)d_in[10];

  char* ws = (char*)d_ws;
  ushort* wcat_t = (ushort*)(ws);                     //  4 MiB: [2048][1024] bf16
  ushort* wo_t   = (ushort*)(ws + ((size_t)4  << 20)); //  2 MiB: [1024][1024] bf16
  float*  bcat   = (float*) (ws + ((size_t)6  << 20)); //  8 KiB
  float4* agg    = (float4*)(ws + ((size_t)8  << 20)); //  4 MiB: [128][2048]
  float2* h0     = (float2*)(ws + ((size_t)12 << 20)); //  2 MiB: [128][2048]
  ushort* xb     = (ushort*)(ws + ((size_t)16 << 20)); // 32 MiB: x bf16, later out bf16
  float*  lin    = (float*) (ws + ((size_t)48 << 20)); // 128 MiB: lin, later y (first 64)

  // weight prep
  tconv<<<dim3(512 / 32, 1024 / 32), dim3(32, 8), 0, stream>>>(Wt, 1024, 512, wcat_t, 0);
  tconv<<<dim3(512 / 32, 1024 / 32), dim3(32, 8), 0, stream>>>(Wr, 1024, 512, wcat_t, 512);
  tconv<<<dim3(1024 / 32, 1024 / 32), dim3(32, 8), 0, stream>>>(Wi, 1024, 1024, wcat_t, 1024);
  tconv<<<dim3(1024 / 32, 1024 / 32), dim3(32, 8), 0, stream>>>(Wo, 1024, 1024, wo_t, 0);
  pack_bias<<<8, 256, 0, stream>>>(bt, br, bi, bcat);
  xconv<<<16384, 256, 0, stream>>>((const float4*)x, xb, 4194304);

  // lin = x @ [Wt|Wr|Wi] + [bt|br|bi]   (M=16384 N=2048 K=1024)
  gemm256<<<512, 512, 0, stream>>>(xb, wcat_t, lin, bcat, nullptr, 16384, 2048, 1024, 8);

  // chunked complex scan
  scan_k1<<<dim3(8, 128), 256, 0, stream>>>(lin, agg);
  scan_k2<<<8, 256, 0, stream>>>(agg, h0);
  scan_k3<<<dim3(8, 128), 256, 0, stream>>>(lin, h0, xb /* -> out bf16, x dead */);

  // y = x + out @ Wo + bo   (M=16384 N=1024 K=1024; y overwrites lin)
  gemm256<<<256, 512, 0, stream>>>(xb, wo_t, lin, bo, x, 16384, 1024, 1024, 4);

  // layernorm -> d_out
  ln_k<<<16384, 256, 0, stream>>>(lin, gamma, beta, (float*)d_out);
}

// Round 3
// 274.999 us; speedup vs baseline: 1.1137x; 1.0679x over previous
//
#include <hip/hip_runtime.h>
#include <cstdint>

// ---------------------------------------------------------------------------
// RotationScan: theta/retain/inp GEMM -> chunked complex scan -> out GEMM -> LN
// B=4 T=4096 D=1024 SD=512 CHUNK=32
// ---------------------------------------------------------------------------

typedef __bf16 bf16x8 __attribute__((ext_vector_type(8)));
typedef float  f32x4  __attribute__((ext_vector_type(4)));

#define AS1 __attribute__((address_space(1)))
#define AS3 __attribute__((address_space(3)))

__device__ __forceinline__ void gload16(const void* g, void* l) {
  __builtin_amdgcn_global_load_lds((const AS1 void*)g, (AS3 void*)l, 16, 0, 0);
}

__device__ __forceinline__ ushort f2bf(float f) {
  union { float f; uint32_t u; } v; v.f = f;
  uint32_t u = v.u;
  uint32_t r = u + 0x7FFFu + ((u >> 16) & 1u);   // RNE
  return (ushort)(r >> 16);
}

// ---------------------------------------------------------------------------
// Transpose + f32->bf16 convert:  dst[(row_off + c)*R + r] = bf16(src[r*C + c])
// ---------------------------------------------------------------------------
__global__ __launch_bounds__(256) void tconv(const float* __restrict__ src, int R, int C,
                                             ushort* __restrict__ dst, int row_off) {
  __shared__ float tile[32][33];
  int tx = threadIdx.x, ty = threadIdx.y;
  int rb = blockIdx.y * 32, cb = blockIdx.x * 32;
#pragma unroll
  for (int yy = 0; yy < 4; ++yy) {
    int r = rb + ty + yy * 8;
    tile[ty + yy * 8][tx] = src[(size_t)r * C + cb + tx];
  }
  __syncthreads();
#pragma unroll
  for (int yy = 0; yy < 4; ++yy) {
    int c = cb + ty + yy * 8;
    dst[(size_t)(row_off + c) * R + rb + tx] = f2bf(tile[tx][ty + yy * 8]);
  }
}

__global__ __launch_bounds__(256) void pack_bias(const float* __restrict__ bt,
                                                 const float* __restrict__ br,
                                                 const float* __restrict__ bi,
                                                 float* __restrict__ bcat) {
  int i = blockIdx.x * 256 + threadIdx.x;          // 0..2047
  bcat[i] = (i < 512) ? bt[i] : (i < 1024 ? br[i - 512] : bi[i - 1024]);
}

__global__ __launch_bounds__(256) void xconv(const float4* __restrict__ src,
                                             ushort* __restrict__ dst, int n4) {
  int i = blockIdx.x * 256 + threadIdx.x;
  if (i < n4) {
    float4 v = src[i];
    ushort4 o;
    o.x = f2bf(v.x); o.y = f2bf(v.y); o.z = f2bf(v.z); o.w = f2bf(v.w);
    *(ushort4*)(dst + (size_t)i * 4) = o;
  }
}

// ---------------------------------------------------------------------------
// bf16 GEMM: C[M,N](f32) = A[M,K](bf16) @ Bt[N,K](bf16)^T + bias[N] (+ addm[M,N])
// 128x128 tile, BK=64, 4 waves 2x2, XOR-swizzled LDS, global_load_lds (r1 proven).
// 1D grid with XCD-chunked swizzle, bn-fastest inside each XCD chunk:
//   each XCD owns a contiguous bm-band -> A panel + B panel stay L2-resident.
// ---------------------------------------------------------------------------
__global__ __launch_bounds__(256) void gemm_bf16(const ushort* __restrict__ A,
                                                 const ushort* __restrict__ Bt,
                                                 float* __restrict__ C,
                                                 const float* __restrict__ bias,
                                                 const float* __restrict__ addm,
                                                 int M, int N, int K, int nbn) {
  __shared__ alignas(16) ushort Atile[128 * 64];
  __shared__ alignas(16) ushort Btile[128 * 64];

  // XCD-bijective chunk swizzle (gridDim.x % 8 == 0): XCD x gets wg in
  // [x*cpx, (x+1)*cpx); bm = wg/nbn (slow), bn = wg%nbn (fast).
  const int cpx = gridDim.x >> 3;
  const int wg = ((int)blockIdx.x & 7) * cpx + ((int)blockIdx.x >> 3);
  const int bm = wg / nbn, bn = wg % nbn;

  const int t = threadIdx.x;
  const int l = t & 63;
  const int w = t >> 6;
  const int wr = w >> 1, wc = w & 1;

  f32x4 acc[4][4] = {};

  const int m_local0 = t >> 3;       // row covered by this thread within a pass
  const int jslot = t & 7;           // physical 16B slot within the 128B row
  const size_t a_row0 = (size_t)bm * 128 * K;
  const size_t b_row0 = (size_t)bn * 128 * K;

  const int r  = l & 15;
  const int kq = l >> 4;
  const int nkt = K >> 6;

  for (int kt = 0; kt < nkt; ++kt) {
    const int kcol = kt * 64;
    // ---- stage A,B tile (16KB each) with pre-swizzled global source ----
#pragma unroll
    for (int p = 0; p < 4; ++p) {
      int ml = p * 32 + m_local0;
      int s = jslot ^ (ml & 7);                       // logical slot to fetch
      const ushort* ga = A + a_row0 + (size_t)ml * K + kcol + s * 8;
      const ushort* gb = Bt + b_row0 + (size_t)ml * K + kcol + s * 8;
      ushort* la = Atile + (size_t)(p * 256 + w * 64) * 8;   // wave-uniform base
      ushort* lb = Btile + (size_t)(p * 256 + w * 64) * 8;
      gload16(ga, la);
      gload16(gb, lb);
    }
    __syncthreads();   // drains vmcnt then barriers
    // ---- compute: 2 K-steps of 32, 16 MFMA each ----
#pragma unroll
    for (int ks = 0; ks < 2; ++ks) {
      int sA = ks * 4 + kq;                // logical slot for this lane's k-range
      int j = sA ^ (r & 7);                // physical slot after swizzle
      bf16x8 af[4], bfr[4];
#pragma unroll
      for (int i = 0; i < 4; ++i) {
        int m = wr * 64 + i * 16 + r;
        af[i] = *(const bf16x8*)(Atile + (size_t)m * 64 + j * 8);
        int n = wc * 64 + i * 16 + r;
        bfr[i] = *(const bf16x8*)(Btile + (size_t)n * 64 + j * 8);
      }
#pragma unroll
      for (int i = 0; i < 4; ++i)
#pragma unroll
        for (int jn = 0; jn < 4; ++jn)
          acc[i][jn] = __builtin_amdgcn_mfma_f32_16x16x32_bf16(af[i], bfr[jn], acc[i][jn], 0, 0, 0);
    }
    __syncthreads();
  }

  // ---- epilogue: C/D layout col=lane&15, row=(lane>>4)*4+q ----
  const int q4 = (l >> 4) * 4;
#pragma unroll
  for (int i = 0; i < 4; ++i) {
#pragma unroll
    for (int jn = 0; jn < 4; ++jn) {
      int gcol = bn * 128 + wc * 64 + jn * 16 + r;
      float bv = bias ? bias[gcol] : 0.f;
#pragma unroll
      for (int q = 0; q < 4; ++q) {
        int grow = bm * 128 + wr * 64 + i * 16 + q4 + q;
        float v = acc[i][jn][q] + bv;
        if (addm) v += addm[(size_t)grow * N + gcol];
        C[(size_t)grow * N + gcol] = v;
      }
    }
  }
}

// ---------------------------------------------------------------------------
// Scan kernels. lin[row, 2048]: [theta | retain_logit | inp_r | inp_i]
// cum_mag kept as running product (== exp(cumsum(log(clip(rt,1e-6)))) within
// fp32 noise); the 1e-8 clip on the inverse is preserved exactly.
// ---------------------------------------------------------------------------
__global__ __launch_bounds__(256) void scan_k1(const float* __restrict__ lin,
                                               float4* __restrict__ agg) {
  int bd = blockIdx.x * 256 + threadIdx.x;    // 0..2047  (b*512 + d)
  int c  = blockIdx.y;                         // 0..127
  int b  = bd >> 9, d = bd & 511;
  const float* base = lin + ((size_t)b * 4096 + (size_t)c * 32) * 2048;
  float cth = 0.f, cbr = 0.f, cbi = 0.f;
  float cm = 1.f, cs = 1.f, sn = 0.f;
#pragma unroll 4
  for (int t = 0; t < 32; ++t) {
    const float* row = base + (size_t)t * 2048;
    float th = row[d];
    float z  = row[512 + d];
    float ir = row[1024 + d];
    float ii = row[1536 + d];
    float rt = __fdividef(1.f, 1.f + __expf(-z));
    cm *= fmaxf(rt, 1e-6f);
    cth += th;
    float s_, c_;
    __sincosf(cth, &s_, &c_);
    float im = __fdividef(1.f, fmaxf(cm, 1e-8f));
    float invr = im * c_, invi = -im * s_;
    float drive = 1.f - rt;
    float br_ = drive * ir, bi_ = drive * ii;
    cbr += invr * br_ - invi * bi_;
    cbi += invr * bi_ + invi * br_;
    cs = c_; sn = s_;
  }
  agg[(size_t)c * 2048 + bd] = make_float4(cm * cs, cm * sn, cbr, cbi);
}

__global__ __launch_bounds__(256) void scan_k2(const float4* __restrict__ agg,
                                               float2* __restrict__ h0) {
  int bd = blockIdx.x * 256 + threadIdx.x;    // 2048 threads
  float hr = 0.f, hi = 0.f;
  for (int cg = 0; cg < 16; ++cg) {
    float4 a[8];
#pragma unroll
    for (int u = 0; u < 8; ++u) a[u] = agg[(size_t)(cg * 8 + u) * 2048 + bd];
#pragma unroll
    for (int u = 0; u < 8; ++u) {
      h0[(size_t)(cg * 8 + u) * 2048 + bd] = make_float2(hr, hi);
      float tr = hr + a[u].z, ti = hi + a[u].w;
      hr = a[u].x * tr - a[u].y * ti;
      hi = a[u].x * ti + a[u].y * tr;
    }
  }
}

__global__ __launch_bounds__(256) void scan_k3(const float* __restrict__ lin,
                                               const float2* __restrict__ h0,
                                               ushort* __restrict__ outb) {
  int bd = blockIdx.x * 256 + threadIdx.x;
  int c  = blockIdx.y;
  int b  = bd >> 9, d = bd & 511;
  const float* base = lin + ((size_t)b * 4096 + (size_t)c * 32) * 2048;
  float2 h = h0[(size_t)c * 2048 + bd];
  float cth = 0.f, cbr = 0.f, cbi = 0.f, cm = 1.f;
#pragma unroll 4
  for (int t = 0; t < 32; ++t) {
    const float* row = base + (size_t)t * 2048;
    float th = row[d];
    float z  = row[512 + d];
    float ir = row[1024 + d];
    float ii = row[1536 + d];
    float rt = __fdividef(1.f, 1.f + __expf(-z));
    cm *= fmaxf(rt, 1e-6f);
    cth += th;
    float s_, c_;
    __sincosf(cth, &s_, &c_);
    float im = __fdividef(1.f, fmaxf(cm, 1e-8f));
    float invr = im * c_, invi = -im * s_;
    float drive = 1.f - rt;
    float br_ = drive * ir, bi_ = drive * ii;
    cbr += invr * br_ - invi * bi_;
    cbi += invr * bi_ + invi * br_;
    float ar = cm * c_, ai = cm * s_;
    float tr = h.x + cbr, ti = h.y + cbi;
    float orr = ar * tr - ai * ti;
    float oii = ar * ti + ai * tr;
    size_t rowo = ((size_t)b * 4096 + (size_t)c * 32 + t) * 1024;
    outb[rowo + d] = f2bf(orr);
    outb[rowo + 512 + d] = f2bf(oii);
  }
}

// ---------------------------------------------------------------------------
// LayerNorm over D=1024, one block per row.
// ---------------------------------------------------------------------------
__global__ __launch_bounds__(256) void ln_k(const float* __restrict__ y,
                                            const float* __restrict__ gamma,
                                            const float* __restrict__ beta,
                                            float* __restrict__ out) {
  int row = blockIdx.x;
  const float4* yr = (const float4*)(y + (size_t)row * 1024);
  float4 v = yr[threadIdx.x];
  float s  = v.x + v.y + v.z + v.w;
  float s2 = v.x * v.x + v.y * v.y + v.z * v.z + v.w * v.w;
#pragma unroll
  for (int off = 32; off > 0; off >>= 1) {
    s  += __shfl_down(s, off);
    s2 += __shfl_down(s2, off);
  }
  __shared__ float red[8];
  __shared__ float mv[2];
  int l = threadIdx.x & 63, w = threadIdx.x >> 6;
  if (l == 0) { red[w] = s; red[4 + w] = s2; }
  __syncthreads();
  if (threadIdx.x == 0) {
    float ts = red[0] + red[1] + red[2] + red[3];
    float t2 = red[4] + red[5] + red[6] + red[7];
    float mu = ts * (1.f / 1024.f);
    float var = t2 * (1.f / 1024.f) - mu * mu;
    mv[0] = mu;
    mv[1] = 1.f / sqrtf(var + 1e-5f);
  }
  __syncthreads();
  float mu = mv[0], rstd = mv[1];
  const float4* g4 = (const float4*)gamma;
  const float4* b4 = (const float4*)beta;
  float4 gv = g4[threadIdx.x], bv = b4[threadIdx.x];
  float4 o;
  o.x = (v.x - mu) * rstd * gv.x + bv.x;
  o.y = (v.y - mu) * rstd * gv.y + bv.y;
  o.z = (v.z - mu) * rstd * gv.z + bv.z;
  o.w = (v.w - mu) * rstd * gv.w + bv.w;
  ((float4*)(out + (size_t)row * 1024))[threadIdx.x] = o;
}

// ---------------------------------------------------------------------------
extern "C" void kernel_launch(void* const* d_in, const int* in_sizes, int n_in,
                              void* d_out, int out_size, void* d_ws, size_t ws_size,
                              hipStream_t stream) {
  (void)in_sizes; (void)n_in; (void)out_size; (void)ws_size;
  const float* x  = (const float*)d_in[0];
  const float* Wt = (const float*)d_in[1];
  const float* bt = (const float*)d_in[2];
  const float* Wr = (const float*)d_in[3];
  const float* br = (const float*)d_in[4];
  const float* Wi = (const float*)d_in[5];
  const float* bi = (const float*)d_in[6];
  const float* Wo = (const float*)d_in[7];
  const float* bo = (const float*)d_in[8];
  const float* gamma = (const float*)d_in[9];
  const float* beta  = (const float*)d_in[10];

  char* ws = (char*)d_ws;
  ushort* wcat_t = (ushort*)(ws);                     //  4 MiB: [2048][1024] bf16
  ushort* wo_t   = (ushort*)(ws + ((size_t)4  << 20)); //  2 MiB: [1024][1024] bf16
  float*  bcat   = (float*) (ws + ((size_t)6  << 20)); //  8 KiB
  float4* agg    = (float4*)(ws + ((size_t)8  << 20)); //  4 MiB: [128][2048]
  float2* h0     = (float2*)(ws + ((size_t)12 << 20)); //  2 MiB: [128][2048]
  ushort* xb     = (ushort*)(ws + ((size_t)16 << 20)); // 32 MiB: x bf16, later out bf16
  float*  lin    = (float*) (ws + ((size_t)48 << 20)); // 128 MiB: lin, later y (first 64)

  // weight prep
  tconv<<<dim3(512 / 32, 1024 / 32), dim3(32, 8), 0, stream>>>(Wt, 1024, 512, wcat_t, 0);
  tconv<<<dim3(512 / 32, 1024 / 32), dim3(32, 8), 0, stream>>>(Wr, 1024, 512, wcat_t, 512);
  tconv<<<dim3(1024 / 32, 1024 / 32), dim3(32, 8), 0, stream>>>(Wi, 1024, 1024, wcat_t, 1024);
  tconv<<<dim3(1024 / 32, 1024 / 32), dim3(32, 8), 0, stream>>>(Wo, 1024, 1024, wo_t, 0);
  pack_bias<<<8, 256, 0, stream>>>(bt, br, bi, bcat);
  xconv<<<16384, 256, 0, stream>>>((const float4*)x, xb, 4194304);

  // lin = x @ [Wt|Wr|Wi] + [bt|br|bi]   (M=16384 N=2048 K=1024, 2048 blocks)
  gemm_bf16<<<2048, 256, 0, stream>>>(xb, wcat_t, lin, bcat, nullptr, 16384, 2048, 1024, 16);

  // chunked complex scan
  scan_k1<<<dim3(8, 128), 256, 0, stream>>>(lin, agg);
  scan_k2<<<8, 256, 0, stream>>>(agg, h0);
  scan_k3<<<dim3(8, 128), 256, 0, stream>>>(lin, h0, xb /* -> out bf16, x dead */);

  // y = x + out @ Wo + bo   (M=16384 N=1024 K=1024, 1024 blocks; y overwrites lin)
  gemm_bf16<<<1024, 256, 0, stream>>>(xb, wo_t, lin, bo, x, 16384, 1024, 1024, 8);

  // layernorm -> d_out
  ln_k<<<16384, 256, 0, stream>>>(lin, gamma, beta, (float*)d_out);
}

// Round 4
// 257.140 us; speedup vs baseline: 1.1910x; 1.0695x over previous
//
#include <hip/hip_runtime.h>
#include <cstdint>

// ---------------------------------------------------------------------------
// RotationScan: theta/retain/inp GEMM -> chunked complex scan -> out GEMM -> LN
// B=4 T=4096 D=1024 SD=512 CHUNK=32
// ---------------------------------------------------------------------------

typedef __bf16 bf16x8 __attribute__((ext_vector_type(8)));
typedef float  f32x4  __attribute__((ext_vector_type(4)));

#define AS1 __attribute__((address_space(1)))
#define AS3 __attribute__((address_space(3)))

__device__ __forceinline__ void gload16(const void* g, void* l) {
  __builtin_amdgcn_global_load_lds((const AS1 void*)g, (AS3 void*)l, 16, 0, 0);
}

__device__ __forceinline__ ushort f2bf(float f) {
  union { float f; uint32_t u; } v; v.f = f;
  uint32_t u = v.u;
  uint32_t r = u + 0x7FFFu + ((u >> 16) & 1u);   // RNE
  return (ushort)(r >> 16);
}
__device__ __forceinline__ float bf2f(ushort u) {
  union { uint32_t x; float f; } v; v.x = (uint32_t)u << 16; return v.f;
}
__device__ __forceinline__ float ld_f(const float* p, size_t i)  { return p[i]; }
__device__ __forceinline__ float ld_f(const ushort* p, size_t i) { return bf2f(p[i]); }
__device__ __forceinline__ void  st_f(float* p, size_t i, float v)  { p[i] = v; }
__device__ __forceinline__ void  st_f(ushort* p, size_t i, float v) { p[i] = f2bf(v); }

// ---------------------------------------------------------------------------
// Transpose + f32->bf16 convert:  dst[(row_off + c)*R + r] = bf16(src[r*C + c])
// ---------------------------------------------------------------------------
__global__ __launch_bounds__(256) void tconv(const float* __restrict__ src, int R, int C,
                                             ushort* __restrict__ dst, int row_off) {
  __shared__ float tile[32][33];
  int tx = threadIdx.x, ty = threadIdx.y;
  int rb = blockIdx.y * 32, cb = blockIdx.x * 32;
#pragma unroll
  for (int yy = 0; yy < 4; ++yy) {
    int r = rb + ty + yy * 8;
    tile[ty + yy * 8][tx] = src[(size_t)r * C + cb + tx];
  }
  __syncthreads();
#pragma unroll
  for (int yy = 0; yy < 4; ++yy) {
    int c = cb + ty + yy * 8;
    dst[(size_t)(row_off + c) * R + rb + tx] = f2bf(tile[tx][ty + yy * 8]);
  }
}

__global__ __launch_bounds__(256) void pack_bias(const float* __restrict__ bt,
                                                 const float* __restrict__ br,
                                                 const float* __restrict__ bi,
                                                 float* __restrict__ bcat) {
  int i = blockIdx.x * 256 + threadIdx.x;          // 0..2047
  bcat[i] = (i < 512) ? bt[i] : (i < 1024 ? br[i - 512] : bi[i - 1024]);
}

__global__ __launch_bounds__(256) void xconv(const float4* __restrict__ src,
                                             ushort* __restrict__ dst, int n4) {
  int i = blockIdx.x * 256 + threadIdx.x;
  if (i < n4) {
    float4 v = src[i];
    ushort4 o;
    o.x = f2bf(v.x); o.y = f2bf(v.y); o.z = f2bf(v.z); o.w = f2bf(v.w);
    *(ushort4*)(dst + (size_t)i * 4) = o;
  }
}

// ---------------------------------------------------------------------------
// bf16 GEMM: C[M,N] = A[M,K](bf16) @ Bt[N,K](bf16)^T + bias[N] (+ addm[M,N])
// 128x128 tile, BK=64, 4 waves 2x2, XOR-swizzled LDS, global_load_lds.
// Counted-vmcnt pipeline (T3 min + T4): STAGE(next) -> vmcnt(8) waits only for
// PREVIOUS iteration's loads -> raw barrier -> compute -> raw barrier.
// Race audit: buffer overwritten by STAGE was last ds_read one iteration ago,
// sealed by that iteration's end barrier; vmcnt(8) before top barrier makes
// every wave's current-tile loads LDS-visible to all.
// XCD-chunked swizzle, bn-fastest within chunk (r3: FETCH 138->77MB).
// ---------------------------------------------------------------------------
template <typename CT, typename AT>
__global__ __launch_bounds__(256) void gemm_bf16(const ushort* __restrict__ A,
                                                 const ushort* __restrict__ Bt,
                                                 CT* __restrict__ C,
                                                 const float* __restrict__ bias,
                                                 const AT* __restrict__ addm,
                                                 int M, int N, int K, int nbn) {
  __shared__ alignas(16) ushort As[2][128 * 64];
  __shared__ alignas(16) ushort Bs[2][128 * 64];

  const int cpx = gridDim.x >> 3;
  const int wg = ((int)blockIdx.x & 7) * cpx + ((int)blockIdx.x >> 3);
  const int bm = wg / nbn, bn = wg % nbn;

  const int t = threadIdx.x;
  const int l = t & 63;
  const int w = t >> 6;
  const int wr = w >> 1, wc = w & 1;

  f32x4 acc[4][4] = {};

  const int m_local0 = t >> 3;       // row covered by this thread within a pass
  const int jslot = t & 7;           // physical 16B slot within the 128B row
  const size_t a_row0 = (size_t)bm * 128 * K;
  const size_t b_row0 = (size_t)bn * 128 * K;

  const int r  = l & 15;
  const int kq = l >> 4;
  const int nkt = K >> 6;

#define STAGE(buf, kt)                                                         \
  do {                                                                         \
    const int kcol = (kt) * 64;                                                \
    _Pragma("unroll")                                                          \
    for (int p = 0; p < 4; ++p) {                                              \
      int ml = p * 32 + m_local0;                                              \
      int s = jslot ^ (ml & 7);                                                \
      const ushort* ga = A + a_row0 + (size_t)ml * K + kcol + s * 8;           \
      const ushort* gb = Bt + b_row0 + (size_t)ml * K + kcol + s * 8;          \
      ushort* la = As[buf] + (size_t)(p * 256 + w * 64) * 8;                   \
      ushort* lb = Bs[buf] + (size_t)(p * 256 + w * 64) * 8;                   \
      gload16(ga, la);                                                         \
      gload16(gb, lb);                                                         \
    }                                                                          \
  } while (0)

  STAGE(0, 0);   // prologue: 8 loads in flight

  for (int kt = 0; kt < nkt; ++kt) {
    const int cur = kt & 1;
    if (kt + 1 < nkt) {
      STAGE(cur ^ 1, kt + 1);                       // 8 more loads (16 in flight)
      asm volatile("s_waitcnt vmcnt(8)" ::: "memory");   // tile kt landed
    } else {
      asm volatile("s_waitcnt vmcnt(0)" ::: "memory");   // tail drain
    }
    __builtin_amdgcn_s_barrier();                   // all waves' kt loads visible

    // ---- compute: 2 K-steps of 32, 16 MFMA each ----
#pragma unroll
    for (int ks = 0; ks < 2; ++ks) {
      int sA = ks * 4 + kq;                // logical slot for this lane's k-range
      int j = sA ^ (r & 7);                // physical slot after swizzle
      bf16x8 af[4], bfr[4];
#pragma unroll
      for (int i = 0; i < 4; ++i) {
        int m = wr * 64 + i * 16 + r;
        af[i] = *(const bf16x8*)(As[cur] + (size_t)m * 64 + j * 8);
        int n = wc * 64 + i * 16 + r;
        bfr[i] = *(const bf16x8*)(Bs[cur] + (size_t)n * 64 + j * 8);
      }
#pragma unroll
      for (int i = 0; i < 4; ++i)
#pragma unroll
        for (int jn = 0; jn < 4; ++jn)
          acc[i][jn] = __builtin_amdgcn_mfma_f32_16x16x32_bf16(af[i], bfr[jn], acc[i][jn], 0, 0, 0);
    }
    __builtin_amdgcn_s_barrier();                   // reads of buf[cur] done
  }
#undef STAGE

  // ---- epilogue: C/D layout col=lane&15, row=(lane>>4)*4+q ----
  const int q4 = (l >> 4) * 4;
#pragma unroll
  for (int i = 0; i < 4; ++i) {
#pragma unroll
    for (int jn = 0; jn < 4; ++jn) {
      int gcol = bn * 128 + wc * 64 + jn * 16 + r;
      float bv = bias ? bias[gcol] : 0.f;
#pragma unroll
      for (int q = 0; q < 4; ++q) {
        int grow = bm * 128 + wr * 64 + i * 16 + q4 + q;
        float v = acc[i][jn][q] + bv;
        if (addm) v += ld_f(addm, (size_t)grow * N + gcol);
        st_f(C, (size_t)grow * N + gcol, v);
      }
    }
  }
}

// ---------------------------------------------------------------------------
// Scan kernels. lin[row, 2048] (bf16): [theta | retain_logit | inp_r | inp_i]
// cum_mag as running product (== exp(cumsum(log(clip(rt,1e-6)))) within fp32
// noise); the 1e-8 clip on the inverse is preserved exactly.
// ---------------------------------------------------------------------------
__global__ __launch_bounds__(256) void scan_k1(const ushort* __restrict__ lin,
                                               float4* __restrict__ agg) {
  int bd = blockIdx.x * 256 + threadIdx.x;    // 0..2047  (b*512 + d)
  int c  = blockIdx.y;                         // 0..127
  int b  = bd >> 9, d = bd & 511;
  const ushort* base = lin + ((size_t)b * 4096 + (size_t)c * 32) * 2048;
  float cth = 0.f, cbr = 0.f, cbi = 0.f;
  float cm = 1.f, cs = 1.f, sn = 0.f;
#pragma unroll 4
  for (int t = 0; t < 32; ++t) {
    const ushort* row = base + (size_t)t * 2048;
    float th = bf2f(row[d]);
    float z  = bf2f(row[512 + d]);
    float ir = bf2f(row[1024 + d]);
    float ii = bf2f(row[1536 + d]);
    float rt = __fdividef(1.f, 1.f + __expf(-z));
    cm *= fmaxf(rt, 1e-6f);
    cth += th;
    float s_, c_;
    __sincosf(cth, &s_, &c_);
    float im = __fdividef(1.f, fmaxf(cm, 1e-8f));
    float invr = im * c_, invi = -im * s_;
    float drive = 1.f - rt;
    float br_ = drive * ir, bi_ = drive * ii;
    cbr += invr * br_ - invi * bi_;
    cbi += invr * bi_ + invi * br_;
    cs = c_; sn = s_;
  }
  agg[(size_t)c * 2048 + bd] = make_float4(cm * cs, cm * sn, cbr, cbi);
}

__global__ __launch_bounds__(256) void scan_k2(const float4* __restrict__ agg,
                                               float2* __restrict__ h0) {
  int bd = blockIdx.x * 256 + threadIdx.x;    // 2048 threads
  float hr = 0.f, hi = 0.f;
  for (int cg = 0; cg < 16; ++cg) {
    float4 a[8];
#pragma unroll
    for (int u = 0; u < 8; ++u) a[u] = agg[(size_t)(cg * 8 + u) * 2048 + bd];
#pragma unroll
    for (int u = 0; u < 8; ++u) {
      h0[(size_t)(cg * 8 + u) * 2048 + bd] = make_float2(hr, hi);
      float tr = hr + a[u].z, ti = hi + a[u].w;
      hr = a[u].x * tr - a[u].y * ti;
      hi = a[u].x * ti + a[u].y * tr;
    }
  }
}

__global__ __launch_bounds__(256) void scan_k3(const ushort* __restrict__ lin,
                                               const float2* __restrict__ h0,
                                               ushort* __restrict__ outb) {
  int bd = blockIdx.x * 256 + threadIdx.x;
  int c  = blockIdx.y;
  int b  = bd >> 9, d = bd & 511;
  const ushort* base = lin + ((size_t)b * 4096 + (size_t)c * 32) * 2048;
  float2 h = h0[(size_t)c * 2048 + bd];
  float cth = 0.f, cbr = 0.f, cbi = 0.f, cm = 1.f;
#pragma unroll 4
  for (int t = 0; t < 32; ++t) {
    const ushort* row = base + (size_t)t * 2048;
    float th = bf2f(row[d]);
    float z  = bf2f(row[512 + d]);
    float ir = bf2f(row[1024 + d]);
    float ii = bf2f(row[1536 + d]);
    float rt = __fdividef(1.f, 1.f + __expf(-z));
    cm *= fmaxf(rt, 1e-6f);
    cth += th;
    float s_, c_;
    __sincosf(cth, &s_, &c_);
    float im = __fdividef(1.f, fmaxf(cm, 1e-8f));
    float invr = im * c_, invi = -im * s_;
    float drive = 1.f - rt;
    float br_ = drive * ir, bi_ = drive * ii;
    cbr += invr * br_ - invi * bi_;
    cbi += invr * bi_ + invi * br_;
    float ar = cm * c_, ai = cm * s_;
    float tr = h.x + cbr, ti = h.y + cbi;
    float orr = ar * tr - ai * ti;
    float oii = ar * ti + ai * tr;
    size_t rowo = ((size_t)b * 4096 + (size_t)c * 32 + t) * 1024;
    outb[rowo + d] = f2bf(orr);
    outb[rowo + 512 + d] = f2bf(oii);
  }
}

// ---------------------------------------------------------------------------
// LayerNorm over D=1024, one block per row.
// ---------------------------------------------------------------------------
__global__ __launch_bounds__(256) void ln_k(const float* __restrict__ y,
                                            const float* __restrict__ gamma,
                                            const float* __restrict__ beta,
                                            float* __restrict__ out) {
  int row = blockIdx.x;
  const float4* yr = (const float4*)(y + (size_t)row * 1024);
  float4 v = yr[threadIdx.x];
  float s  = v.x + v.y + v.z + v.w;
  float s2 = v.x * v.x + v.y * v.y + v.z * v.z + v.w * v.w;
#pragma unroll
  for (int off = 32; off > 0; off >>= 1) {
    s  += __shfl_down(s, off);
    s2 += __shfl_down(s2, off);
  }
  __shared__ float red[8];
  __shared__ float mv[2];
  int l = threadIdx.x & 63, w = threadIdx.x >> 6;
  if (l == 0) { red[w] = s; red[4 + w] = s2; }
  __syncthreads();
  if (threadIdx.x == 0) {
    float ts = red[0] + red[1] + red[2] + red[3];
    float t2 = red[4] + red[5] + red[6] + red[7];
    float mu = ts * (1.f / 1024.f);
    float var = t2 * (1.f / 1024.f) - mu * mu;
    mv[0] = mu;
    mv[1] = 1.f / sqrtf(var + 1e-5f);
  }
  __syncthreads();
  float mu = mv[0], rstd = mv[1];
  const float4* g4 = (const float4*)gamma;
  const float4* b4 = (const float4*)beta;
  float4 gv = g4[threadIdx.x], bv = b4[threadIdx.x];
  float4 o;
  o.x = (v.x - mu) * rstd * gv.x + bv.x;
  o.y = (v.y - mu) * rstd * gv.y + bv.y;
  o.z = (v.z - mu) * rstd * gv.z + bv.z;
  o.w = (v.w - mu) * rstd * gv.w + bv.w;
  ((float4*)(out + (size_t)row * 1024))[threadIdx.x] = o;
}

// ---------------------------------------------------------------------------
extern "C" void kernel_launch(void* const* d_in, const int* in_sizes, int n_in,
                              void* d_out, int out_size, void* d_ws, size_t ws_size,
                              hipStream_t stream) {
  (void)in_sizes; (void)n_in; (void)out_size; (void)ws_size;
  const float* x  = (const float*)d_in[0];
  const float* Wt = (const float*)d_in[1];
  const float* bt = (const float*)d_in[2];
  const float* Wr = (const float*)d_in[3];
  const float* br = (const float*)d_in[4];
  const float* Wi = (const float*)d_in[5];
  const float* bi = (const float*)d_in[6];
  const float* Wo = (const float*)d_in[7];
  const float* bo = (const float*)d_in[8];
  const float* gamma = (const float*)d_in[9];
  const float* beta  = (const float*)d_in[10];

  char* ws = (char*)d_ws;
  ushort* wcat_t = (ushort*)(ws);                      //  4 MiB: [2048][1024] bf16
  ushort* wo_t   = (ushort*)(ws + ((size_t)4  << 20)); //  2 MiB: [1024][1024] bf16
  float*  bcat   = (float*) (ws + ((size_t)6  << 20)); //  8 KiB
  float4* agg    = (float4*)(ws + ((size_t)8  << 20)); //  4 MiB: [128][2048]
  float2* h0     = (float2*)(ws + ((size_t)12 << 20)); //  2 MiB: [128][2048]
  ushort* xb     = (ushort*)(ws + ((size_t)16 << 20)); // 32 MiB: x bf16 (alive thru GEMM2)
  ushort* outb   = (ushort*)(ws + ((size_t)48 << 20)); // 32 MiB: scan out bf16
  ushort* linb   = (ushort*)(ws + ((size_t)80 << 20)); // 64 MiB: lin bf16
  float*  y      = (float*) (ws + ((size_t)80 << 20)); // 64 MiB: y f32 (overlays dead linb)

  // weight prep
  tconv<<<dim3(512 / 32, 1024 / 32), dim3(32, 8), 0, stream>>>(Wt, 1024, 512, wcat_t, 0);
  tconv<<<dim3(512 / 32, 1024 / 32), dim3(32, 8), 0, stream>>>(Wr, 1024, 512, wcat_t, 512);
  tconv<<<dim3(1024 / 32, 1024 / 32), dim3(32, 8), 0, stream>>>(Wi, 1024, 1024, wcat_t, 1024);
  tconv<<<dim3(1024 / 32, 1024 / 32), dim3(32, 8), 0, stream>>>(Wo, 1024, 1024, wo_t, 0);
  pack_bias<<<8, 256, 0, stream>>>(bt, br, bi, bcat);
  xconv<<<16384, 256, 0, stream>>>((const float4*)x, xb, 4194304);

  // lin(bf16) = x @ [Wt|Wr|Wi] + [bt|br|bi]   (M=16384 N=2048 K=1024)
  gemm_bf16<ushort, float><<<2048, 256, 0, stream>>>(
      xb, wcat_t, linb, bcat, (const float*)nullptr, 16384, 2048, 1024, 16);

  // chunked complex scan
  scan_k1<<<dim3(8, 128), 256, 0, stream>>>(linb, agg);
  scan_k2<<<8, 256, 0, stream>>>(agg, h0);
  scan_k3<<<dim3(8, 128), 256, 0, stream>>>(linb, h0, outb);

  // y(f32) = x(bf16) + out @ Wo + bo   (M=16384 N=1024 K=1024; y overlays linb)
  gemm_bf16<float, ushort><<<1024, 256, 0, stream>>>(
      outb, wo_t, y, bo, xb, 16384, 1024, 1024, 8);

  // layernorm -> d_out
  ln_k<<<16384, 256, 0, stream>>>(y, gamma, beta, (float*)d_out);
}

// Round 5
// 244.091 us; speedup vs baseline: 1.2547x; 1.0535x over previous
//
#include <hip/hip_runtime.h>
#include <cstdint>

// ---------------------------------------------------------------------------
// RotationScan: theta/retain/inp GEMM -> chunked complex scan -> out GEMM -> LN
// B=4 T=4096 D=1024 SD=512 CHUNK=32
// ---------------------------------------------------------------------------

typedef __bf16 bf16x8 __attribute__((ext_vector_type(8)));
typedef float  f32x4  __attribute__((ext_vector_type(4)));

#define AS1 __attribute__((address_space(1)))
#define AS3 __attribute__((address_space(3)))

__device__ __forceinline__ void gload16(const void* g, void* l) {
  __builtin_amdgcn_global_load_lds((const AS1 void*)g, (AS3 void*)l, 16, 0, 0);
}

__device__ __forceinline__ ushort f2bf(float f) {
  union { float f; uint32_t u; } v; v.f = f;
  uint32_t u = v.u;
  uint32_t r = u + 0x7FFFu + ((u >> 16) & 1u);   // RNE
  return (ushort)(r >> 16);
}
__device__ __forceinline__ float bf2f(ushort u) {
  union { uint32_t x; float f; } v; v.x = (uint32_t)u << 16; return v.f;
}
__device__ __forceinline__ float ld_f(const float* p, size_t i)  { return p[i]; }
__device__ __forceinline__ float ld_f(const ushort* p, size_t i) { return bf2f(p[i]); }
__device__ __forceinline__ void  st_f(float* p, size_t i, float v)  { p[i] = v; }
__device__ __forceinline__ void  st_f(ushort* p, size_t i, float v) { p[i] = f2bf(v); }

// ---------------------------------------------------------------------------
// Transpose + f32->bf16 convert:  dst[(row_off + c)*R + r] = bf16(src[r*C + c])
// ---------------------------------------------------------------------------
__global__ __launch_bounds__(256) void tconv(const float* __restrict__ src, int R, int C,
                                             ushort* __restrict__ dst, int row_off) {
  __shared__ float tile[32][33];
  int tx = threadIdx.x, ty = threadIdx.y;
  int rb = blockIdx.y * 32, cb = blockIdx.x * 32;
#pragma unroll
  for (int yy = 0; yy < 4; ++yy) {
    int r = rb + ty + yy * 8;
    tile[ty + yy * 8][tx] = src[(size_t)r * C + cb + tx];
  }
  __syncthreads();
#pragma unroll
  for (int yy = 0; yy < 4; ++yy) {
    int c = cb + ty + yy * 8;
    dst[(size_t)(row_off + c) * R + rb + tx] = f2bf(tile[tx][ty + yy * 8]);
  }
}

__global__ __launch_bounds__(256) void pack_bias(const float* __restrict__ bt,
                                                 const float* __restrict__ br,
                                                 const float* __restrict__ bi,
                                                 float* __restrict__ bcat) {
  int i = blockIdx.x * 256 + threadIdx.x;          // 0..2047
  bcat[i] = (i < 512) ? bt[i] : (i < 1024 ? br[i - 512] : bi[i - 1024]);
}

__global__ __launch_bounds__(256) void xconv(const float4* __restrict__ src,
                                             ushort* __restrict__ dst, int n4) {
  int i = blockIdx.x * 256 + threadIdx.x;
  if (i < n4) {
    float4 v = src[i];
    ushort4 o;
    o.x = f2bf(v.x); o.y = f2bf(v.y); o.z = f2bf(v.z); o.w = f2bf(v.w);
    *(ushort4*)(dst + (size_t)i * 4) = o;
  }
}

// ---------------------------------------------------------------------------
// 256x256 tile, BK=64, 8 waves (2Mx4N), double-buffered 128 KiB LDS.
// Pipeline: issue ALL of tile kt+1's 8 global_load_lds at top of tile kt,
// then vmcnt(8) = wait ONLY for tile kt's loads; kt+1's stay in flight
// across the barrier (r2's vmcnt(0)-per-tile drain was the mistake).
// 2 raw barriers per K-tile (64 MFMA/wave between sync points).
// Race audit:
//   RAW: each wave vmcnt's its OWN tile-kt loads, then top barrier ->
//        all waves' kt loads LDS-visible before any ds_read.
//   WAR: STAGE at iter kt+1 writes buf (kt+2)&1 = buf read during iter kt,
//        sealed by iter kt's end barrier (program-order before).
//   Compiler motion pinned by "memory" clobbers at both barrier sites.
// Fragment/epilogue math identical to r2's verified gemm256.
// XCD-chunked swizzle, bn-fastest (r3: FETCH 138->77MB).
// ---------------------------------------------------------------------------
template <typename CT, typename AT>
__global__ __launch_bounds__(512, 2) void gemm256(const ushort* __restrict__ A,
                                                  const ushort* __restrict__ Bt,
                                                  CT* __restrict__ C,
                                                  const float* __restrict__ bias,
                                                  const AT* __restrict__ addm,
                                                  int M, int N, int K, int nbn) {
  __shared__ alignas(16) ushort As[2][256 * 64];
  __shared__ alignas(16) ushort Bs[2][256 * 64];

  const int cpx = gridDim.x >> 3;
  const int wg = ((int)blockIdx.x & 7) * cpx + ((int)blockIdx.x >> 3);
  const int bm = wg / nbn, bn = wg % nbn;

  const int t = threadIdx.x;
  const int l = t & 63, w = t >> 6;
  const int wm = w >> 2, wn = w & 3;            // wave grid 2(M) x 4(N)
  const int r = l & 15, kq = l >> 4;

  const size_t a0 = (size_t)bm * 256 * K;
  const size_t b0 = (size_t)bn * 256 * K;

  // staging map: pass u covers rows u*64 + (t>>3); slot fetched = (t&7)^(row&7)
  const int srow = t >> 3;                       // 0..63
  const int sslot = (t & 7) ^ (srow & 7);
  const ushort* gA = A + a0 + (size_t)srow * K + sslot * 8;
  const ushort* gB = Bt + b0 + (size_t)srow * K + sslot * 8;
  const int lboff = w * 1024 + l * 16;           // LDS byte offset (linear dest)

  f32x4 acc[8][4] = {};
  const int NKT = K >> 6;

#define STAGE(buf, kt)                                                         \
  do {                                                                         \
    const int kcol = (kt) * 64;                                                \
    _Pragma("unroll")                                                          \
    for (int u = 0; u < 4; ++u) {                                              \
      gload16(gA + (size_t)(u * 64) * K + kcol, (char*)As[buf] + u * 8192 + lboff); \
      gload16(gB + (size_t)(u * 64) * K + kcol, (char*)Bs[buf] + u * 8192 + lboff); \
    }                                                                          \
  } while (0)

  STAGE(0, 0);   // prologue: tile 0's 8 loads in flight

  for (int kt = 0; kt < NKT; ++kt) {
    const int cur = kt & 1;
    if (kt + 1 < NKT) {
      STAGE(cur ^ 1, kt + 1);                          // 8 more (16 in flight)
      asm volatile("s_waitcnt vmcnt(8)" ::: "memory"); // tile kt landed; kt+1 stays in flight
    } else {
      asm volatile("s_waitcnt vmcnt(0)" ::: "memory"); // tail
    }
    __builtin_amdgcn_s_barrier();                      // all waves' kt loads visible

    // B fragments once per K-tile (reused by all 4 phases)
    bf16x8 bF[4][2];
#pragma unroll
    for (int jn = 0; jn < 4; ++jn) {
      const int row = wn * 64 + jn * 16 + r;
#pragma unroll
      for (int ks = 0; ks < 2; ++ks) {
        const int j = (ks * 4 + kq) ^ (r & 7);
        bF[jn][ks] = *(const bf16x8*)&Bs[cur][row * 64 + j * 8];
      }
    }
#pragma unroll
    for (int ph = 0; ph < 4; ++ph) {
      bf16x8 aF[2][2];
#pragma unroll
      for (int ii = 0; ii < 2; ++ii) {
        const int row = wm * 128 + (ph * 2 + ii) * 16 + r;
#pragma unroll
        for (int ks = 0; ks < 2; ++ks) {
          const int j = (ks * 4 + kq) ^ (r & 7);
          aF[ii][ks] = *(const bf16x8*)&As[cur][row * 64 + j * 8];
        }
      }
      __builtin_amdgcn_s_setprio(1);
#pragma unroll
      for (int ii = 0; ii < 2; ++ii)
#pragma unroll
        for (int jn = 0; jn < 4; ++jn)
#pragma unroll
          for (int ks = 0; ks < 2; ++ks)
            acc[ph * 2 + ii][jn] = __builtin_amdgcn_mfma_f32_16x16x32_bf16(
                aF[ii][ks], bF[jn][ks], acc[ph * 2 + ii][jn], 0, 0, 0);
      __builtin_amdgcn_s_setprio(0);
    }

    asm volatile("" ::: "memory");                 // pin reads above end barrier
    __builtin_amdgcn_s_barrier();                  // seal buf[cur] reads (WAR)
  }
#undef STAGE

  // epilogue: C/D layout col=lane&15, row=(lane>>4)*4+q (verified r1/r2)
  const int q4 = (l >> 4) * 4;
#pragma unroll
  for (int i = 0; i < 8; ++i) {
#pragma unroll
    for (int jn = 0; jn < 4; ++jn) {
      const int gcol = bn * 256 + wn * 64 + jn * 16 + r;
      const float bv = bias ? bias[gcol] : 0.f;
#pragma unroll
      for (int q = 0; q < 4; ++q) {
        const int grow = bm * 256 + wm * 128 + i * 16 + q4 + q;
        float v = acc[i][jn][q] + bv;
        if (addm) v += ld_f(addm, (size_t)grow * N + gcol);
        st_f(C, (size_t)grow * N + gcol, v);
      }
    }
  }
}

// ---------------------------------------------------------------------------
// Scan kernels. lin[row, 2048] (bf16): [theta | retain_logit | inp_r | inp_i]
// cum_mag as running product (== exp(cumsum(log(clip(rt,1e-6)))) within fp32
// noise); the 1e-8 clip on the inverse is preserved exactly.
// ---------------------------------------------------------------------------
__global__ __launch_bounds__(256) void scan_k1(const ushort* __restrict__ lin,
                                               float4* __restrict__ agg) {
  int bd = blockIdx.x * 256 + threadIdx.x;    // 0..2047  (b*512 + d)
  int c  = blockIdx.y;                         // 0..127
  int b  = bd >> 9, d = bd & 511;
  const ushort* base = lin + ((size_t)b * 4096 + (size_t)c * 32) * 2048;
  float cth = 0.f, cbr = 0.f, cbi = 0.f;
  float cm = 1.f, cs = 1.f, sn = 0.f;
#pragma unroll 4
  for (int t = 0; t < 32; ++t) {
    const ushort* row = base + (size_t)t * 2048;
    float th = bf2f(row[d]);
    float z  = bf2f(row[512 + d]);
    float ir = bf2f(row[1024 + d]);
    float ii = bf2f(row[1536 + d]);
    float rt = __fdividef(1.f, 1.f + __expf(-z));
    cm *= fmaxf(rt, 1e-6f);
    cth += th;
    float s_, c_;
    __sincosf(cth, &s_, &c_);
    float im = __fdividef(1.f, fmaxf(cm, 1e-8f));
    float invr = im * c_, invi = -im * s_;
    float drive = 1.f - rt;
    float br_ = drive * ir, bi_ = drive * ii;
    cbr += invr * br_ - invi * bi_;
    cbi += invr * bi_ + invi * br_;
    cs = c_; sn = s_;
  }
  agg[(size_t)c * 2048 + bd] = make_float4(cm * cs, cm * sn, cbr, cbi);
}

__global__ __launch_bounds__(256) void scan_k2(const float4* __restrict__ agg,
                                               float2* __restrict__ h0) {
  int bd = blockIdx.x * 256 + threadIdx.x;    // 2048 threads
  float hr = 0.f, hi = 0.f;
  for (int cg = 0; cg < 16; ++cg) {
    float4 a[8];
#pragma unroll
    for (int u = 0; u < 8; ++u) a[u] = agg[(size_t)(cg * 8 + u) * 2048 + bd];
#pragma unroll
    for (int u = 0; u < 8; ++u) {
      h0[(size_t)(cg * 8 + u) * 2048 + bd] = make_float2(hr, hi);
      float tr = hr + a[u].z, ti = hi + a[u].w;
      hr = a[u].x * tr - a[u].y * ti;
      hi = a[u].x * ti + a[u].y * tr;
    }
  }
}

__global__ __launch_bounds__(256) void scan_k3(const ushort* __restrict__ lin,
                                               const float2* __restrict__ h0,
                                               ushort* __restrict__ outb) {
  int bd = blockIdx.x * 256 + threadIdx.x;
  int c  = blockIdx.y;
  int b  = bd >> 9, d = bd & 511;
  const ushort* base = lin + ((size_t)b * 4096 + (size_t)c * 32) * 2048;
  float2 h = h0[(size_t)c * 2048 + bd];
  float cth = 0.f, cbr = 0.f, cbi = 0.f, cm = 1.f;
#pragma unroll 4
  for (int t = 0; t < 32; ++t) {
    const ushort* row = base + (size_t)t * 2048;
    float th = bf2f(row[d]);
    float z  = bf2f(row[512 + d]);
    float ir = bf2f(row[1024 + d]);
    float ii = bf2f(row[1536 + d]);
    float rt = __fdividef(1.f, 1.f + __expf(-z));
    cm *= fmaxf(rt, 1e-6f);
    cth += th;
    float s_, c_;
    __sincosf(cth, &s_, &c_);
    float im = __fdividef(1.f, fmaxf(cm, 1e-8f));
    float invr = im * c_, invi = -im * s_;
    float drive = 1.f - rt;
    float br_ = drive * ir, bi_ = drive * ii;
    cbr += invr * br_ - invi * bi_;
    cbi += invr * bi_ + invi * br_;
    float ar = cm * c_, ai = cm * s_;
    float tr = h.x + cbr, ti = h.y + cbi;
    float orr = ar * tr - ai * ti;
    float oii = ar * ti + ai * tr;
    size_t rowo = ((size_t)b * 4096 + (size_t)c * 32 + t) * 1024;
    outb[rowo + d] = f2bf(orr);
    outb[rowo + 512 + d] = f2bf(oii);
  }
}

// ---------------------------------------------------------------------------
// LayerNorm over D=1024, one block per row; y is bf16.
// ---------------------------------------------------------------------------
__global__ __launch_bounds__(256) void ln_k(const ushort* __restrict__ y,
                                            const float* __restrict__ gamma,
                                            const float* __restrict__ beta,
                                            float* __restrict__ out) {
  int row = blockIdx.x;
  const ushort4* yr = (const ushort4*)(y + (size_t)row * 1024);
  ushort4 u = yr[threadIdx.x];
  float4 v;
  v.x = bf2f(u.x); v.y = bf2f(u.y); v.z = bf2f(u.z); v.w = bf2f(u.w);
  float s  = v.x + v.y + v.z + v.w;
  float s2 = v.x * v.x + v.y * v.y + v.z * v.z + v.w * v.w;
#pragma unroll
  for (int off = 32; off > 0; off >>= 1) {
    s  += __shfl_down(s, off);
    s2 += __shfl_down(s2, off);
  }
  __shared__ float red[8];
  __shared__ float mv[2];
  int l = threadIdx.x & 63, w = threadIdx.x >> 6;
  if (l == 0) { red[w] = s; red[4 + w] = s2; }
  __syncthreads();
  if (threadIdx.x == 0) {
    float ts = red[0] + red[1] + red[2] + red[3];
    float t2 = red[4] + red[5] + red[6] + red[7];
    float mu = ts * (1.f / 1024.f);
    float var = t2 * (1.f / 1024.f) - mu * mu;
    mv[0] = mu;
    mv[1] = 1.f / sqrtf(var + 1e-5f);
  }
  __syncthreads();
  float mu = mv[0], rstd = mv[1];
  const float4* g4 = (const float4*)gamma;
  const float4* b4 = (const float4*)beta;
  float4 gv = g4[threadIdx.x], bv = b4[threadIdx.x];
  float4 o;
  o.x = (v.x - mu) * rstd * gv.x + bv.x;
  o.y = (v.y - mu) * rstd * gv.y + bv.y;
  o.z = (v.z - mu) * rstd * gv.z + bv.z;
  o.w = (v.w - mu) * rstd * gv.w + bv.w;
  ((float4*)(out + (size_t)row * 1024))[threadIdx.x] = o;
}

// ---------------------------------------------------------------------------
extern "C" void kernel_launch(void* const* d_in, const int* in_sizes, int n_in,
                              void* d_out, int out_size, void* d_ws, size_t ws_size,
                              hipStream_t stream) {
  (void)in_sizes; (void)n_in; (void)out_size; (void)ws_size;
  const float* x  = (const float*)d_in[0];
  const float* Wt = (const float*)d_in[1];
  const float* bt = (const float*)d_in[2];
  const float* Wr = (const float*)d_in[3];
  const float* br = (const float*)d_in[4];
  const float* Wi = (const float*)d_in[5];
  const float* bi = (const float*)d_in[6];
  const float* Wo = (const float*)d_in[7];
  const float* bo = (const float*)d_in[8];
  const float* gamma = (const float*)d_in[9];
  const float* beta  = (const float*)d_in[10];

  char* ws = (char*)d_ws;
  ushort* wcat_t = (ushort*)(ws);                      //  4 MiB: [2048][1024] bf16
  ushort* wo_t   = (ushort*)(ws + ((size_t)4  << 20)); //  2 MiB: [1024][1024] bf16
  float*  bcat   = (float*) (ws + ((size_t)6  << 20)); //  8 KiB
  float4* agg    = (float4*)(ws + ((size_t)8  << 20)); //  4 MiB: [128][2048]
  float2* h0     = (float2*)(ws + ((size_t)12 << 20)); //  2 MiB: [128][2048]
  ushort* xb     = (ushort*)(ws + ((size_t)16 << 20)); // 32 MiB: x bf16 (alive thru GEMM2)
  ushort* outb   = (ushort*)(ws + ((size_t)48 << 20)); // 32 MiB: scan out bf16
  ushort* linb   = (ushort*)(ws + ((size_t)80 << 20)); // 64 MiB: lin bf16
  ushort* yb     = (ushort*)(ws + ((size_t)80 << 20)); // 32 MiB: y bf16 (overlays dead linb)

  // weight prep
  tconv<<<dim3(512 / 32, 1024 / 32), dim3(32, 8), 0, stream>>>(Wt, 1024, 512, wcat_t, 0);
  tconv<<<dim3(512 / 32, 1024 / 32), dim3(32, 8), 0, stream>>>(Wr, 1024, 512, wcat_t, 512);
  tconv<<<dim3(1024 / 32, 1024 / 32), dim3(32, 8), 0, stream>>>(Wi, 1024, 1024, wcat_t, 1024);
  tconv<<<dim3(1024 / 32, 1024 / 32), dim3(32, 8), 0, stream>>>(Wo, 1024, 1024, wo_t, 0);
  pack_bias<<<8, 256, 0, stream>>>(bt, br, bi, bcat);
  xconv<<<16384, 256, 0, stream>>>((const float4*)x, xb, 4194304);

  // lin(bf16) = x @ [Wt|Wr|Wi] + [bt|br|bi]   (M=16384 N=2048 K=1024, 512 blocks)
  gemm256<ushort, float><<<512, 512, 0, stream>>>(
      xb, wcat_t, linb, bcat, (const float*)nullptr, 16384, 2048, 1024, 8);

  // chunked complex scan
  scan_k1<<<dim3(8, 128), 256, 0, stream>>>(linb, agg);
  scan_k2<<<8, 256, 0, stream>>>(agg, h0);
  scan_k3<<<dim3(8, 128), 256, 0, stream>>>(linb, h0, outb);

  // y(bf16) = x(bf16) + out @ Wo + bo   (M=16384 N=1024 K=1024, 256 blocks)
  gemm256<ushort, ushort><<<256, 512, 0, stream>>>(
      outb, wo_t, yb, bo, xb, 16384, 1024, 1024, 4);

  // layernorm -> d_out
  ln_k<<<16384, 256, 0, stream>>>(yb, gamma, beta, (float*)d_out);
}

// Round 6
// 228.731 us; speedup vs baseline: 1.3390x; 1.0672x over previous
//
#include <hip/hip_runtime.h>
#include <cstdint>

// ---------------------------------------------------------------------------
// RotationScan: theta/retain/inp GEMM -> chunked complex scan -> out GEMM -> LN
// B=4 T=4096 D=1024 SD=512 CHUNK=32
// ---------------------------------------------------------------------------

typedef __bf16 bf16x8 __attribute__((ext_vector_type(8)));
typedef float  f32x4  __attribute__((ext_vector_type(4)));

#define AS1 __attribute__((address_space(1)))
#define AS3 __attribute__((address_space(3)))

__device__ __forceinline__ void gload16(const void* g, void* l) {
  __builtin_amdgcn_global_load_lds((const AS1 void*)g, (AS3 void*)l, 16, 0, 0);
}

__device__ __forceinline__ ushort f2bf(float f) {
  union { float f; uint32_t u; } v; v.f = f;
  uint32_t u = v.u;
  uint32_t r = u + 0x7FFFu + ((u >> 16) & 1u);   // RNE
  return (ushort)(r >> 16);
}
__device__ __forceinline__ float bf2f(ushort u) {
  union { uint32_t x; float f; } v; v.x = (uint32_t)u << 16; return v.f;
}
__device__ __forceinline__ void st_f(float* p, size_t i, float v)  { p[i] = v; }
__device__ __forceinline__ void st_f(ushort* p, size_t i, float v) { p[i] = f2bf(v); }

// ---------------------------------------------------------------------------
// Transpose + f32->bf16 convert:  dst[(row_off + c)*R + r] = bf16(src[r*C + c])
// ---------------------------------------------------------------------------
__global__ __launch_bounds__(256) void tconv(const float* __restrict__ src, int R, int C,
                                             ushort* __restrict__ dst, int row_off) {
  __shared__ float tile[32][33];
  int tx = threadIdx.x, ty = threadIdx.y;
  int rb = blockIdx.y * 32, cb = blockIdx.x * 32;
#pragma unroll
  for (int yy = 0; yy < 4; ++yy) {
    int r = rb + ty + yy * 8;
    tile[ty + yy * 8][tx] = src[(size_t)r * C + cb + tx];
  }
  __syncthreads();
#pragma unroll
  for (int yy = 0; yy < 4; ++yy) {
    int c = cb + ty + yy * 8;
    dst[(size_t)(row_off + c) * R + rb + tx] = f2bf(tile[tx][ty + yy * 8]);
  }
}

__global__ __launch_bounds__(256) void pack_bias(const float* __restrict__ bt,
                                                 const float* __restrict__ br,
                                                 const float* __restrict__ bi,
                                                 float* __restrict__ bcat) {
  int i = blockIdx.x * 256 + threadIdx.x;          // 0..2047
  bcat[i] = (i < 512) ? bt[i] : (i < 1024 ? br[i - 512] : bi[i - 1024]);
}

__global__ __launch_bounds__(256) void xconv(const float4* __restrict__ src,
                                             ushort* __restrict__ dst, int n4) {
  int i = blockIdx.x * 256 + threadIdx.x;
  if (i < n4) {
    float4 v = src[i];
    ushort4 o;
    o.x = f2bf(v.x); o.y = f2bf(v.y); o.z = f2bf(v.z); o.w = f2bf(v.w);
    *(ushort4*)(dst + (size_t)i * 4) = o;
  }
}

// ---------------------------------------------------------------------------
// 256x256 tile, BK=64, 8 waves (2Mx4N), double-buffered 128 KiB LDS.
// 4 fine phases per K-tile, 2 barriers per K-tile, counted vmcnt.
//
// Staging order per K-tile kt (staging kt+1): P0:{B0,B1} P1:{B2,B3}
// P2:{A0,A2} P3:{A1,A3}  (pass u = rows u*64..u*64+63, 1 gload/wave each).
// Read schedule of K-tile kt: P0 reads bF(all)+aF stripe0, P1 stripe1
// (A-passes 0,2), P2 stripe2, P3 stripe3 (A-passes 1,3).
// vmcnt ledger: @P0 wait vmcnt(4): 4 newest = {B0,B1(kt+1), A1,A3(kt)} ->
//   B(kt)+A0,A2(kt) landed. @P2 wait vmcnt(6): 6 newest = kt+1's 6 staged
//   so far -> A1,A3(kt) landed. Tail (no staging): vmcnt(2)/vmcnt(0).
// Barrier after each wait makes landings visible to ALL waves (every wave
// executed the same wait before the same barrier).
// WAR audit: Bs[nxt] last read kt-1.P0 (sealed >=2 barriers before issue);
// As[nxt] last read kt-1.P2/P3 (sealed by kt.P0 barrier, before P2/P3 issue);
// fast waves entering kt+1.P0 stage Bs[cur], whose bF reads sealed at kt.P2
// barrier. All landing sites read-sealed before issue.
// ---------------------------------------------------------------------------
template <typename CT>
__global__ __launch_bounds__(512, 2) void gemm256(const ushort* __restrict__ A,
                                                  const ushort* __restrict__ Bt,
                                                  CT* __restrict__ C,
                                                  const float* __restrict__ bias,
                                                  int M, int N, int K, int nbn) {
  __shared__ alignas(16) ushort As[2][256 * 64];
  __shared__ alignas(16) ushort Bs[2][256 * 64];

  const int cpx = gridDim.x >> 3;
  const int wg = ((int)blockIdx.x & 7) * cpx + ((int)blockIdx.x >> 3);
  const int bm = wg / nbn, bn = wg % nbn;

  const int t = threadIdx.x;
  const int l = t & 63, w = t >> 6;
  const int wm = w >> 2, wn = w & 3;            // wave grid 2(M) x 4(N)
  const int r = l & 15, kq = l >> 4;

  const size_t a0 = (size_t)bm * 256 * K;
  const size_t b0 = (size_t)bn * 256 * K;

  const int srow = t >> 3;                       // 0..63
  const int sslot = (t & 7) ^ (srow & 7);
  const ushort* gA = A + a0 + (size_t)srow * K + sslot * 8;
  const ushort* gB = Bt + b0 + (size_t)srow * K + sslot * 8;
  const int lboff = w * 1024 + l * 16;           // LDS byte offset

  f32x4 acc[8][4] = {};
  const int NKT = K >> 6;

#define STG(G, LB, kt, u) \
  gload16((G) + (size_t)((u) * 64) * K + (size_t)(kt) * 64, (char*)(LB) + (u) * 8192 + lboff)

#define QUAD(ph)                                                               \
  do {                                                                         \
    bf16x8 aF[2][2];                                                           \
    _Pragma("unroll")                                                          \
    for (int ii = 0; ii < 2; ++ii) {                                           \
      const int row = wm * 128 + ((ph) * 2 + ii) * 16 + r;                     \
      _Pragma("unroll")                                                        \
      for (int ks = 0; ks < 2; ++ks) {                                         \
        const int j = (ks * 4 + kq) ^ (r & 7);                                 \
        aF[ii][ks] = *(const bf16x8*)&As[cur][row * 64 + j * 8];               \
      }                                                                        \
    }                                                                          \
    __builtin_amdgcn_s_setprio(1);                                             \
    _Pragma("unroll")                                                          \
    for (int ii = 0; ii < 2; ++ii)                                             \
      _Pragma("unroll")                                                        \
      for (int jn = 0; jn < 4; ++jn)                                           \
        _Pragma("unroll")                                                      \
        for (int ks = 0; ks < 2; ++ks)                                         \
          acc[(ph) * 2 + ii][jn] = __builtin_amdgcn_mfma_f32_16x16x32_bf16(    \
              aF[ii][ks], bF[jn][ks], acc[(ph) * 2 + ii][jn], 0, 0, 0);        \
    __builtin_amdgcn_s_setprio(0);                                             \
  } while (0)

  // prologue: K-tile 0, exact ledger order B0,B1,B2,B3,A0,A2,A1,A3
  STG(gB, Bs[0], 0, 0); STG(gB, Bs[0], 0, 1);
  STG(gB, Bs[0], 0, 2); STG(gB, Bs[0], 0, 3);
  STG(gA, As[0], 0, 0); STG(gA, As[0], 0, 2);
  STG(gA, As[0], 0, 1); STG(gA, As[0], 0, 3);

  for (int kt = 0; kt < NKT; ++kt) {
    const int cur = kt & 1, nxt = cur ^ 1;
    const bool hn = (kt + 1 < NKT);
    // ---------------- phase 0 ----------------
    if (hn) { STG(gB, Bs[nxt], kt + 1, 0); STG(gB, Bs[nxt], kt + 1, 1); }
    if (hn) asm volatile("s_waitcnt vmcnt(4)" ::: "memory");
    else    asm volatile("s_waitcnt vmcnt(2)" ::: "memory");
    __builtin_amdgcn_s_barrier();
    asm volatile("" ::: "memory");
    bf16x8 bF[4][2];
#pragma unroll
    for (int jn = 0; jn < 4; ++jn) {
      const int row = wn * 64 + jn * 16 + r;
#pragma unroll
      for (int ks = 0; ks < 2; ++ks) {
        const int j = (ks * 4 + kq) ^ (r & 7);
        bF[jn][ks] = *(const bf16x8*)&Bs[cur][row * 64 + j * 8];
      }
    }
    QUAD(0);
    // ---------------- phase 1 ----------------
    if (hn) { STG(gB, Bs[nxt], kt + 1, 2); STG(gB, Bs[nxt], kt + 1, 3); }
    QUAD(1);
    // ---------------- phase 2 ----------------
    if (hn) { STG(gA, As[nxt], kt + 1, 0); STG(gA, As[nxt], kt + 1, 2); }
    if (hn) asm volatile("s_waitcnt vmcnt(6)" ::: "memory");
    else    asm volatile("s_waitcnt vmcnt(0)" ::: "memory");
    __builtin_amdgcn_s_barrier();
    asm volatile("" ::: "memory");
    QUAD(2);
    // ---------------- phase 3 ----------------
    if (hn) { STG(gA, As[nxt], kt + 1, 1); STG(gA, As[nxt], kt + 1, 3); }
    QUAD(3);
  }
#undef STG
#undef QUAD

  // epilogue: C/D layout col=lane&15, row=(lane>>4)*4+q (verified r1/r2)
  const int q4 = (l >> 4) * 4;
#pragma unroll
  for (int i = 0; i < 8; ++i) {
#pragma unroll
    for (int jn = 0; jn < 4; ++jn) {
      const int gcol = bn * 256 + wn * 64 + jn * 16 + r;
      const float bv = bias ? bias[gcol] : 0.f;
#pragma unroll
      for (int q = 0; q < 4; ++q) {
        const int grow = bm * 256 + wm * 128 + i * 16 + q4 + q;
        st_f(C, (size_t)grow * N + gcol, acc[i][jn][q] + bv);
      }
    }
  }
}

// ---------------------------------------------------------------------------
// Scan kernels. lin[row, 2048] (bf16): [theta | retain_logit | inp_r | inp_i]
// cum_mag as running product (== exp(cumsum(log(clip(rt,1e-6)))) within fp32
// noise); the 1e-8 clip on the inverse is preserved exactly.
// ---------------------------------------------------------------------------
__global__ __launch_bounds__(256) void scan_k1(const ushort* __restrict__ lin,
                                               float4* __restrict__ agg) {
  int bd = blockIdx.x * 256 + threadIdx.x;    // 0..2047  (b*512 + d)
  int c  = blockIdx.y;                         // 0..127
  int b  = bd >> 9, d = bd & 511;
  const ushort* base = lin + ((size_t)b * 4096 + (size_t)c * 32) * 2048;
  float cth = 0.f, cbr = 0.f, cbi = 0.f;
  float cm = 1.f, cs = 1.f, sn = 0.f;
#pragma unroll 4
  for (int t = 0; t < 32; ++t) {
    const ushort* row = base + (size_t)t * 2048;
    float th = bf2f(row[d]);
    float z  = bf2f(row[512 + d]);
    float ir = bf2f(row[1024 + d]);
    float ii = bf2f(row[1536 + d]);
    float rt = __fdividef(1.f, 1.f + __expf(-z));
    cm *= fmaxf(rt, 1e-6f);
    cth += th;
    float s_, c_;
    __sincosf(cth, &s_, &c_);
    float im = __fdividef(1.f, fmaxf(cm, 1e-8f));
    float invr = im * c_, invi = -im * s_;
    float drive = 1.f - rt;
    float br_ = drive * ir, bi_ = drive * ii;
    cbr += invr * br_ - invi * bi_;
    cbi += invr * bi_ + invi * br_;
    cs = c_; sn = s_;
  }
  agg[(size_t)c * 2048 + bd] = make_float4(cm * cs, cm * sn, cbr, cbi);
}

__global__ __launch_bounds__(256) void scan_k2(const float4* __restrict__ agg,
                                               float2* __restrict__ h0) {
  int bd = blockIdx.x * 256 + threadIdx.x;    // 2048 threads
  float hr = 0.f, hi = 0.f;
  for (int cg = 0; cg < 16; ++cg) {
    float4 a[8];
#pragma unroll
    for (int u = 0; u < 8; ++u) a[u] = agg[(size_t)(cg * 8 + u) * 2048 + bd];
#pragma unroll
    for (int u = 0; u < 8; ++u) {
      h0[(size_t)(cg * 8 + u) * 2048 + bd] = make_float2(hr, hi);
      float tr = hr + a[u].z, ti = hi + a[u].w;
      hr = a[u].x * tr - a[u].y * ti;
      hi = a[u].x * ti + a[u].y * tr;
    }
  }
}

__global__ __launch_bounds__(256) void scan_k3(const ushort* __restrict__ lin,
                                               const float2* __restrict__ h0,
                                               ushort* __restrict__ outb) {
  int bd = blockIdx.x * 256 + threadIdx.x;
  int c  = blockIdx.y;
  int b  = bd >> 9, d = bd & 511;
  const ushort* base = lin + ((size_t)b * 4096 + (size_t)c * 32) * 2048;
  float2 h = h0[(size_t)c * 2048 + bd];
  float cth = 0.f, cbr = 0.f, cbi = 0.f, cm = 1.f;
#pragma unroll 4
  for (int t = 0; t < 32; ++t) {
    const ushort* row = base + (size_t)t * 2048;
    float th = bf2f(row[d]);
    float z  = bf2f(row[512 + d]);
    float ir = bf2f(row[1024 + d]);
    float ii = bf2f(row[1536 + d]);
    float rt = __fdividef(1.f, 1.f + __expf(-z));
    cm *= fmaxf(rt, 1e-6f);
    cth += th;
    float s_, c_;
    __sincosf(cth, &s_, &c_);
    float im = __fdividef(1.f, fmaxf(cm, 1e-8f));
    float invr = im * c_, invi = -im * s_;
    float drive = 1.f - rt;
    float br_ = drive * ir, bi_ = drive * ii;
    cbr += invr * br_ - invi * bi_;
    cbi += invr * bi_ + invi * br_;
    float ar = cm * c_, ai = cm * s_;
    float tr = h.x + cbr, ti = h.y + cbi;
    float orr = ar * tr - ai * ti;
    float oii = ar * ti + ai * tr;
    size_t rowo = ((size_t)b * 4096 + (size_t)c * 32 + t) * 1024;
    outb[rowo + d] = f2bf(orr);
    outb[rowo + 512 + d] = f2bf(oii);
  }
}

// ---------------------------------------------------------------------------
// LayerNorm over D=1024, one block per row; y = yb + xb (residual fused here).
// ---------------------------------------------------------------------------
__global__ __launch_bounds__(256) void ln_k(const ushort* __restrict__ yb,
                                            const ushort* __restrict__ xb,
                                            const float* __restrict__ gamma,
                                            const float* __restrict__ beta,
                                            float* __restrict__ out) {
  int row = blockIdx.x;
  ushort4 uy = ((const ushort4*)(yb + (size_t)row * 1024))[threadIdx.x];
  ushort4 ux = ((const ushort4*)(xb + (size_t)row * 1024))[threadIdx.x];
  float4 v;
  v.x = bf2f(uy.x) + bf2f(ux.x);
  v.y = bf2f(uy.y) + bf2f(ux.y);
  v.z = bf2f(uy.z) + bf2f(ux.z);
  v.w = bf2f(uy.w) + bf2f(ux.w);
  float s  = v.x + v.y + v.z + v.w;
  float s2 = v.x * v.x + v.y * v.y + v.z * v.z + v.w * v.w;
#pragma unroll
  for (int off = 32; off > 0; off >>= 1) {
    s  += __shfl_down(s, off);
    s2 += __shfl_down(s2, off);
  }
  __shared__ float red[8];
  __shared__ float mv[2];
  int l = threadIdx.x & 63, w = threadIdx.x >> 6;
  if (l == 0) { red[w] = s; red[4 + w] = s2; }
  __syncthreads();
  if (threadIdx.x == 0) {
    float ts = red[0] + red[1] + red[2] + red[3];
    float t2 = red[4] + red[5] + red[6] + red[7];
    float mu = ts * (1.f / 1024.f);
    float var = t2 * (1.f / 1024.f) - mu * mu;
    mv[0] = mu;
    mv[1] = 1.f / sqrtf(var + 1e-5f);
  }
  __syncthreads();
  float mu = mv[0], rstd = mv[1];
  const float4* g4 = (const float4*)gamma;
  const float4* b4 = (const float4*)beta;
  float4 gv = g4[threadIdx.x], bv = b4[threadIdx.x];
  float4 o;
  o.x = (v.x - mu) * rstd * gv.x + bv.x;
  o.y = (v.y - mu) * rstd * gv.y + bv.y;
  o.z = (v.z - mu) * rstd * gv.z + bv.z;
  o.w = (v.w - mu) * rstd * gv.w + bv.w;
  ((float4*)(out + (size_t)row * 1024))[threadIdx.x] = o;
}

// ---------------------------------------------------------------------------
extern "C" void kernel_launch(void* const* d_in, const int* in_sizes, int n_in,
                              void* d_out, int out_size, void* d_ws, size_t ws_size,
                              hipStream_t stream) {
  (void)in_sizes; (void)n_in; (void)out_size; (void)ws_size;
  const float* x  = (const float*)d_in[0];
  const float* Wt = (const float*)d_in[1];
  const float* bt = (const float*)d_in[2];
  const float* Wr = (const float*)d_in[3];
  const float* br = (const float*)d_in[4];
  const float* Wi = (const float*)d_in[5];
  const float* bi = (const float*)d_in[6];
  const float* Wo = (const float*)d_in[7];
  const float* bo = (const float*)d_in[8];
  const float* gamma = (const float*)d_in[9];
  const float* beta  = (const float*)d_in[10];

  char* ws = (char*)d_ws;
  ushort* wcat_t = (ushort*)(ws);                      //  4 MiB: [2048][1024] bf16
  ushort* wo_t   = (ushort*)(ws + ((size_t)4  << 20)); //  2 MiB: [1024][1024] bf16
  float*  bcat   = (float*) (ws + ((size_t)6  << 20)); //  8 KiB
  float4* agg    = (float4*)(ws + ((size_t)8  << 20)); //  4 MiB: [128][2048]
  float2* h0     = (float2*)(ws + ((size_t)12 << 20)); //  2 MiB: [128][2048]
  ushort* xb     = (ushort*)(ws + ((size_t)16 << 20)); // 32 MiB: x bf16 (alive thru ln_k)
  ushort* outb   = (ushort*)(ws + ((size_t)48 << 20)); // 32 MiB: scan out bf16
  ushort* linb   = (ushort*)(ws + ((size_t)80 << 20)); // 64 MiB: lin bf16
  ushort* yb     = (ushort*)(ws + ((size_t)80 << 20)); // 32 MiB: y bf16 (overlays dead linb)

  // weight prep
  tconv<<<dim3(512 / 32, 1024 / 32), dim3(32, 8), 0, stream>>>(Wt, 1024, 512, wcat_t, 0);
  tconv<<<dim3(512 / 32, 1024 / 32), dim3(32, 8), 0, stream>>>(Wr, 1024, 512, wcat_t, 512);
  tconv<<<dim3(1024 / 32, 1024 / 32), dim3(32, 8), 0, stream>>>(Wi, 1024, 1024, wcat_t, 1024);
  tconv<<<dim3(1024 / 32, 1024 / 32), dim3(32, 8), 0, stream>>>(Wo, 1024, 1024, wo_t, 0);
  pack_bias<<<8, 256, 0, stream>>>(bt, br, bi, bcat);
  xconv<<<16384, 256, 0, stream>>>((const float4*)x, xb, 4194304);

  // lin(bf16) = x @ [Wt|Wr|Wi] + [bt|br|bi]   (M=16384 N=2048 K=1024, 512 blocks)
  gemm256<ushort><<<512, 512, 0, stream>>>(
      xb, wcat_t, linb, bcat, 16384, 2048, 1024, 8);

  // chunked complex scan
  scan_k1<<<dim3(8, 128), 256, 0, stream>>>(linb, agg);
  scan_k2<<<8, 256, 0, stream>>>(agg, h0);
  scan_k3<<<dim3(8, 128), 256, 0, stream>>>(linb, h0, outb);

  // yb(bf16) = out @ Wo + bo   (M=16384 N=1024 K=1024, 256 blocks)
  gemm256<ushort><<<256, 512, 0, stream>>>(
      outb, wo_t, yb, bo, 16384, 1024, 1024, 4);

  // layernorm(yb + xb) -> d_out
  ln_k<<<16384, 256, 0, stream>>>(yb, xb, gamma, beta, (float*)d_out);
}

// Round 7
// 213.345 us; speedup vs baseline: 1.4355x; 1.0721x over previous
//
#include <hip/hip_runtime.h>
#include <cstdint>

// ---------------------------------------------------------------------------
// RotationScan: theta/retain/inp GEMM -> chunked complex scan -> out GEMM -> LN
// B=4 T=4096 D=1024 SD=512 CHUNK=32
// ---------------------------------------------------------------------------

typedef __bf16 bf16x8 __attribute__((ext_vector_type(8)));
typedef float  f32x4  __attribute__((ext_vector_type(4)));
typedef ushort u16x8  __attribute__((ext_vector_type(8)));

#define AS1 __attribute__((address_space(1)))
#define AS3 __attribute__((address_space(3)))

__device__ __forceinline__ void gload16(const void* g, void* l) {
  __builtin_amdgcn_global_load_lds((const AS1 void*)g, (AS3 void*)l, 16, 0, 0);
}

__device__ __forceinline__ ushort f2bf(float f) {
  union { float f; uint32_t u; } v; v.f = f;
  uint32_t u = v.u;
  uint32_t r = u + 0x7FFFu + ((u >> 16) & 1u);   // RNE
  return (ushort)(r >> 16);
}
__device__ __forceinline__ float bf2f(ushort u) {
  union { uint32_t x; float f; } v; v.x = (uint32_t)u << 16; return v.f;
}

// ---------------------------------------------------------------------------
// Transpose + f32->bf16 convert:  dst[(row_off + c)*R + r] = bf16(src[r*C + c])
// ---------------------------------------------------------------------------
__global__ __launch_bounds__(256) void tconv(const float* __restrict__ src, int R, int C,
                                             ushort* __restrict__ dst, int row_off) {
  __shared__ float tile[32][33];
  int tx = threadIdx.x, ty = threadIdx.y;
  int rb = blockIdx.y * 32, cb = blockIdx.x * 32;
#pragma unroll
  for (int yy = 0; yy < 4; ++yy) {
    int r = rb + ty + yy * 8;
    tile[ty + yy * 8][tx] = src[(size_t)r * C + cb + tx];
  }
  __syncthreads();
#pragma unroll
  for (int yy = 0; yy < 4; ++yy) {
    int c = cb + ty + yy * 8;
    dst[(size_t)(row_off + c) * R + rb + tx] = f2bf(tile[tx][ty + yy * 8]);
  }
}

__global__ __launch_bounds__(256) void pack_bias(const float* __restrict__ bt,
                                                 const float* __restrict__ br,
                                                 const float* __restrict__ bi,
                                                 float* __restrict__ bcat) {
  int i = blockIdx.x * 256 + threadIdx.x;          // 0..2047
  bcat[i] = (i < 512) ? bt[i] : (i < 1024 ? br[i - 512] : bi[i - 1024]);
}

__global__ __launch_bounds__(256) void xconv(const float4* __restrict__ src,
                                             ushort* __restrict__ dst, int n4) {
  int i = blockIdx.x * 256 + threadIdx.x;
  if (i < n4) {
    float4 v = src[i];
    ushort4 o;
    o.x = f2bf(v.x); o.y = f2bf(v.y); o.z = f2bf(v.z); o.w = f2bf(v.w);
    *(ushort4*)(dst + (size_t)i * 4) = o;
  }
}

// ---------------------------------------------------------------------------
// BM x 256 tile (BM = 256 or 128), BK=64, 8 waves (2Mx4N), double-buffered LDS.
// 4 fine phases per K-tile, 2 barriers per K-tile, counted vmcnt (r5-verified
// ledger for BM=256; BM=128 ledger re-derived below).
//
// BM=256 (8 gloads/tile): P0:{B0,B1} P1:{B2,B3} P2:{A0,A2} P3:{A1,A3};
//   waits: P0 vmcnt(4) [tail 2], P2 vmcnt(6) [tail 0].
// BM=128 (6 gloads/tile): P0:{B0,B1} P1:{B2,B3} P2:{A0} P3:{A1};
//   P0 wait vmcnt(2) non-tail (2 newest = B0,B1(kt+1); forces ALL of kt in,
//   incl. A0,A1 — every QUAD may need either A pass since wm selects pass),
//   tail vmcnt(0). P2: barrier only (A already landed at P0's wait).
// WAR: Bs[nxt] staged P0/P1, last read kt-1.P0, sealed by kt-1.P2 barrier;
//   As[nxt] staged P2/P3, last read kt-1 QUADs, sealed by kt.P0 barrier;
//   Bs[cur] staged by fast waves at kt+1.P0, bF reads sealed by kt.P2 barrier.
//
// Epilogue: stage area is dead after the K-loop -> write C-tile (bf16, +bias)
// into LDS with 16B-chunk XOR swizzle (pch = chunk ^ (row&7)), barrier, then
// fully-coalesced 16B/lane readback + global_store_dwordx4 (full 64B lines;
// fixes GEMM2's 2x HBM write amplification and the 128-scalar-store storm).
// ---------------------------------------------------------------------------
template <int BM>
__global__ __launch_bounds__(512, 2) void gemm256(const ushort* __restrict__ A,
                                                  const ushort* __restrict__ Bt,
                                                  ushort* __restrict__ C,
                                                  const float* __restrict__ bias,
                                                  int M, int N, int K, int nbn) {
  constexpr int MI = BM / 32;            // acc row-groups per wave (8 or 4)
  constexpr int II = BM / 128;           // row-groups per phase (2 or 1)
  constexpr int STAGE_USH = 2 * (BM * 64 + 256 * 64);
  constexpr int CT_USH = BM * 256;
  constexpr int SM_USH = (STAGE_USH > CT_USH) ? STAGE_USH : CT_USH;
  __shared__ alignas(16) ushort smem[SM_USH];
  ushort* const As0 = smem;                       // As(buf) = As0 + buf*BM*64
  ushort* const Bs0 = smem + 2 * BM * 64;         // Bs(buf) = Bs0 + buf*256*64

  const int cpx = gridDim.x >> 3;
  const int wg = ((int)blockIdx.x & 7) * cpx + ((int)blockIdx.x >> 3);
  const int bm = wg / nbn, bn = wg % nbn;

  const int t = threadIdx.x;
  const int l = t & 63, w = t >> 6;
  const int wm = w >> 2, wn = w & 3;              // wave grid 2(M) x 4(N)
  const int r = l & 15, kq = l >> 4;

  const size_t a0 = (size_t)bm * BM * K;
  const size_t b0 = (size_t)bn * 256 * K;

  const int srow = t >> 3;                        // 0..63
  const int sslot = (t & 7) ^ (srow & 7);
  const ushort* gA = A + a0 + (size_t)srow * K + sslot * 8;
  const ushort* gB = Bt + b0 + (size_t)srow * K + sslot * 8;
  const int lboff = w * 1024 + l * 16;            // LDS byte offset in a pass

  f32x4 acc[MI][4] = {};
  const int NKT = K >> 6;

#define STGA(buf, kt, u) \
  gload16(gA + (size_t)((u) * 64) * K + (size_t)(kt) * 64, \
          (char*)(As0 + (buf) * BM * 64) + (u) * 8192 + lboff)
#define STGB(buf, kt, u) \
  gload16(gB + (size_t)((u) * 64) * K + (size_t)(kt) * 64, \
          (char*)(Bs0 + (buf) * 256 * 64) + (u) * 8192 + lboff)

#define QUAD(ph)                                                               \
  do {                                                                         \
    _Pragma("unroll")                                                          \
    for (int ii = 0; ii < II; ++ii) {                                          \
      bf16x8 aF[2];                                                            \
      const int rowa = wm * (BM / 2) + ((ph) * II + ii) * 16 + r;              \
      _Pragma("unroll")                                                        \
      for (int ks = 0; ks < 2; ++ks) {                                         \
        const int j = (ks * 4 + kq) ^ (r & 7);                                 \
        aF[ks] = *(const bf16x8*)&pA[rowa * 64 + j * 8];                       \
      }                                                                        \
      __builtin_amdgcn_s_setprio(1);                                           \
      _Pragma("unroll")                                                        \
      for (int jn = 0; jn < 4; ++jn)                                           \
        _Pragma("unroll")                                                      \
        for (int ks = 0; ks < 2; ++ks)                                         \
          acc[(ph) * II + ii][jn] = __builtin_amdgcn_mfma_f32_16x16x32_bf16(   \
              aF[ks], bF[jn][ks], acc[(ph) * II + ii][jn], 0, 0, 0);           \
      __builtin_amdgcn_s_setprio(0);                                           \
    }                                                                          \
  } while (0)

  // prologue: tile 0 in ledger order
  STGB(0, 0, 0); STGB(0, 0, 1); STGB(0, 0, 2); STGB(0, 0, 3);
  if constexpr (BM == 256) { STGA(0, 0, 0); STGA(0, 0, 2); STGA(0, 0, 1); STGA(0, 0, 3); }
  else                     { STGA(0, 0, 0); STGA(0, 0, 1); }

  for (int kt = 0; kt < NKT; ++kt) {
    const int cur = kt & 1, nxt = cur ^ 1;
    const bool hn = (kt + 1 < NKT);
    const ushort* pA = As0 + cur * BM * 64;
    const ushort* pB = Bs0 + cur * 256 * 64;
    // ---------------- phase 0 ----------------
    if (hn) { STGB(nxt, kt + 1, 0); STGB(nxt, kt + 1, 1); }
    if constexpr (BM == 256) {
      if (hn) asm volatile("s_waitcnt vmcnt(4)" ::: "memory");
      else    asm volatile("s_waitcnt vmcnt(2)" ::: "memory");
    } else {
      if (hn) asm volatile("s_waitcnt vmcnt(2)" ::: "memory");
      else    asm volatile("s_waitcnt vmcnt(0)" ::: "memory");
    }
    __builtin_amdgcn_s_barrier();
    asm volatile("" ::: "memory");
    bf16x8 bF[4][2];
#pragma unroll
    for (int jn = 0; jn < 4; ++jn) {
      const int rowb = wn * 64 + jn * 16 + r;
#pragma unroll
      for (int ks = 0; ks < 2; ++ks) {
        const int j = (ks * 4 + kq) ^ (r & 7);
        bF[jn][ks] = *(const bf16x8*)&pB[rowb * 64 + j * 8];
      }
    }
    QUAD(0);
    // ---------------- phase 1 ----------------
    if (hn) { STGB(nxt, kt + 1, 2); STGB(nxt, kt + 1, 3); }
    QUAD(1);
    // ---------------- phase 2 ----------------
    if (hn) {
      if constexpr (BM == 256) { STGA(nxt, kt + 1, 0); STGA(nxt, kt + 1, 2); }
      else                     { STGA(nxt, kt + 1, 0); }
    }
    if constexpr (BM == 256) {
      if (hn) asm volatile("s_waitcnt vmcnt(6)" ::: "memory");
      else    asm volatile("s_waitcnt vmcnt(0)" ::: "memory");
    }
    __builtin_amdgcn_s_barrier();
    asm volatile("" ::: "memory");
    QUAD(2);
    // ---------------- phase 3 ----------------
    if (hn) {
      if constexpr (BM == 256) { STGA(nxt, kt + 1, 1); STGA(nxt, kt + 1, 3); }
      else                     { STGA(nxt, kt + 1, 1); }
    }
    QUAD(3);
  }
#undef STGA
#undef STGB
#undef QUAD

  // ---- epilogue via LDS: swizzled scatter, then coalesced 16B stores ----
  asm volatile("s_waitcnt lgkmcnt(0) vmcnt(0)" ::: "memory");
  __builtin_amdgcn_s_barrier();                   // all waves done with stage LDS

  const int q4 = (l >> 4) * 4;
  float bvj[4];
#pragma unroll
  for (int jn = 0; jn < 4; ++jn) {
    const int col = wn * 64 + jn * 16 + r;
    bvj[jn] = bias ? bias[bn * 256 + col] : 0.f;
  }
#pragma unroll
  for (int i = 0; i < MI; ++i) {
#pragma unroll
    for (int jn = 0; jn < 4; ++jn) {
      const int col = wn * 64 + jn * 16 + r;
      const int chunk = col >> 3;
#pragma unroll
      for (int q = 0; q < 4; ++q) {
        const int rowl = wm * (BM / 2) + i * 16 + q4 + q;
        const int pch = chunk ^ (rowl & 7);
        smem[rowl * 256 + pch * 8 + (col & 7)] = f2bf(acc[i][jn][q] + bvj[jn]);
      }
    }
  }
  __builtin_amdgcn_s_barrier();

  const int rrow0 = t >> 5;                       // 0..15
  const int rch = t & 31;                         // logical 16B chunk
#pragma unroll
  for (int p = 0; p < BM / 16; ++p) {
    const int rowl = p * 16 + rrow0;
    const int pch = rch ^ (rowl & 7);
    u16x8 vv = *(const u16x8*)&smem[rowl * 256 + pch * 8];
    const size_t grow = (size_t)(bm * BM + rowl);
    *(u16x8*)&C[grow * N + bn * 256 + rch * 8] = vv;
  }
}

// ---------------------------------------------------------------------------
// Scan kernels. lin[row, 2048] (bf16): [theta | retain_logit | inp_r | inp_i]
// cum_mag as running product (== exp(cumsum(log(clip(rt,1e-6)))) within fp32
// noise); the 1e-8 clip on the inverse is preserved exactly.
// ---------------------------------------------------------------------------
__global__ __launch_bounds__(256) void scan_k1(const ushort* __restrict__ lin,
                                               float4* __restrict__ agg) {
  int bd = blockIdx.x * 256 + threadIdx.x;    // 0..2047  (b*512 + d)
  int c  = blockIdx.y;                         // 0..127
  int b  = bd >> 9, d = bd & 511;
  const ushort* base = lin + ((size_t)b * 4096 + (size_t)c * 32) * 2048;
  float cth = 0.f, cbr = 0.f, cbi = 0.f;
  float cm = 1.f, cs = 1.f, sn = 0.f;
#pragma unroll 4
  for (int t = 0; t < 32; ++t) {
    const ushort* row = base + (size_t)t * 2048;
    float th = bf2f(row[d]);
    float z  = bf2f(row[512 + d]);
    float ir = bf2f(row[1024 + d]);
    float ii = bf2f(row[1536 + d]);
    float rt = __fdividef(1.f, 1.f + __expf(-z));
    cm *= fmaxf(rt, 1e-6f);
    cth += th;
    float s_, c_;
    __sincosf(cth, &s_, &c_);
    float im = __fdividef(1.f, fmaxf(cm, 1e-8f));
    float invr = im * c_, invi = -im * s_;
    float drive = 1.f - rt;
    float br_ = drive * ir, bi_ = drive * ii;
    cbr += invr * br_ - invi * bi_;
    cbi += invr * bi_ + invi * br_;
    cs = c_; sn = s_;
  }
  agg[(size_t)c * 2048 + bd] = make_float4(cm * cs, cm * sn, cbr, cbi);
}

__global__ __launch_bounds__(256) void scan_k2(const float4* __restrict__ agg,
                                               float2* __restrict__ h0) {
  int bd = blockIdx.x * 256 + threadIdx.x;    // 2048 threads
  float hr = 0.f, hi = 0.f;
  for (int cg = 0; cg < 16; ++cg) {
    float4 a[8];
#pragma unroll
    for (int u = 0; u < 8; ++u) a[u] = agg[(size_t)(cg * 8 + u) * 2048 + bd];
#pragma unroll
    for (int u = 0; u < 8; ++u) {
      h0[(size_t)(cg * 8 + u) * 2048 + bd] = make_float2(hr, hi);
      float tr = hr + a[u].z, ti = hi + a[u].w;
      hr = a[u].x * tr - a[u].y * ti;
      hi = a[u].x * ti + a[u].y * tr;
    }
  }
}

__global__ __launch_bounds__(256) void scan_k3(const ushort* __restrict__ lin,
                                               const float2* __restrict__ h0,
                                               ushort* __restrict__ outb) {
  int bd = blockIdx.x * 256 + threadIdx.x;
  int c  = blockIdx.y;
  int b  = bd >> 9, d = bd & 511;
  const ushort* base = lin + ((size_t)b * 4096 + (size_t)c * 32) * 2048;
  float2 h = h0[(size_t)c * 2048 + bd];
  float cth = 0.f, cbr = 0.f, cbi = 0.f, cm = 1.f;
#pragma unroll 4
  for (int t = 0; t < 32; ++t) {
    const ushort* row = base + (size_t)t * 2048;
    float th = bf2f(row[d]);
    float z  = bf2f(row[512 + d]);
    float ir = bf2f(row[1024 + d]);
    float ii = bf2f(row[1536 + d]);
    float rt = __fdividef(1.f, 1.f + __expf(-z));
    cm *= fmaxf(rt, 1e-6f);
    cth += th;
    float s_, c_;
    __sincosf(cth, &s_, &c_);
    float im = __fdividef(1.f, fmaxf(cm, 1e-8f));
    float invr = im * c_, invi = -im * s_;
    float drive = 1.f - rt;
    float br_ = drive * ir, bi_ = drive * ii;
    cbr += invr * br_ - invi * bi_;
    cbi += invr * bi_ + invi * br_;
    float ar = cm * c_, ai = cm * s_;
    float tr = h.x + cbr, ti = h.y + cbi;
    float orr = ar * tr - ai * ti;
    float oii = ar * ti + ai * tr;
    size_t rowo = ((size_t)b * 4096 + (size_t)c * 32 + t) * 1024;
    outb[rowo + d] = f2bf(orr);
    outb[rowo + 512 + d] = f2bf(oii);
  }
}

// ---------------------------------------------------------------------------
// LayerNorm over D=1024, one block per row; y = yb + xb (residual fused here).
// ---------------------------------------------------------------------------
__global__ __launch_bounds__(256) void ln_k(const ushort* __restrict__ yb,
                                            const ushort* __restrict__ xb,
                                            const float* __restrict__ gamma,
                                            const float* __restrict__ beta,
                                            float* __restrict__ out) {
  int row = blockIdx.x;
  ushort4 uy = ((const ushort4*)(yb + (size_t)row * 1024))[threadIdx.x];
  ushort4 ux = ((const ushort4*)(xb + (size_t)row * 1024))[threadIdx.x];
  float4 v;
  v.x = bf2f(uy.x) + bf2f(ux.x);
  v.y = bf2f(uy.y) + bf2f(ux.y);
  v.z = bf2f(uy.z) + bf2f(ux.z);
  v.w = bf2f(uy.w) + bf2f(ux.w);
  float s  = v.x + v.y + v.z + v.w;
  float s2 = v.x * v.x + v.y * v.y + v.z * v.z + v.w * v.w;
#pragma unroll
  for (int off = 32; off > 0; off >>= 1) {
    s  += __shfl_down(s, off);
    s2 += __shfl_down(s2, off);
  }
  __shared__ float red[8];
  __shared__ float mv[2];
  int l = threadIdx.x & 63, w = threadIdx.x >> 6;
  if (l == 0) { red[w] = s; red[4 + w] = s2; }
  __syncthreads();
  if (threadIdx.x == 0) {
    float ts = red[0] + red[1] + red[2] + red[3];
    float t2 = red[4] + red[5] + red[6] + red[7];
    float mu = ts * (1.f / 1024.f);
    float var = t2 * (1.f / 1024.f) - mu * mu;
    mv[0] = mu;
    mv[1] = 1.f / sqrtf(var + 1e-5f);
  }
  __syncthreads();
  float mu = mv[0], rstd = mv[1];
  const float4* g4 = (const float4*)gamma;
  const float4* b4 = (const float4*)beta;
  float4 gv = g4[threadIdx.x], bv = b4[threadIdx.x];
  float4 o;
  o.x = (v.x - mu) * rstd * gv.x + bv.x;
  o.y = (v.y - mu) * rstd * gv.y + bv.y;
  o.z = (v.z - mu) * rstd * gv.z + bv.z;
  o.w = (v.w - mu) * rstd * gv.w + bv.w;
  ((float4*)(out + (size_t)row * 1024))[threadIdx.x] = o;
}

// ---------------------------------------------------------------------------
extern "C" void kernel_launch(void* const* d_in, const int* in_sizes, int n_in,
                              void* d_out, int out_size, void* d_ws, size_t ws_size,
                              hipStream_t stream) {
  (void)in_sizes; (void)n_in; (void)out_size; (void)ws_size;
  const float* x  = (const float*)d_in[0];
  const float* Wt = (const float*)d_in[1];
  const float* bt = (const float*)d_in[2];
  const float* Wr = (const float*)d_in[3];
  const float* br = (const float*)d_in[4];
  const float* Wi = (const float*)d_in[5];
  const float* bi = (const float*)d_in[6];
  const float* Wo = (const float*)d_in[7];
  const float* bo = (const float*)d_in[8];
  const float* gamma = (const float*)d_in[9];
  const float* beta  = (const float*)d_in[10];

  char* ws = (char*)d_ws;
  ushort* wcat_t = (ushort*)(ws);                      //  4 MiB: [2048][1024] bf16
  ushort* wo_t   = (ushort*)(ws + ((size_t)4  << 20)); //  2 MiB: [1024][1024] bf16
  float*  bcat   = (float*) (ws + ((size_t)6  << 20)); //  8 KiB
  float4* agg    = (float4*)(ws + ((size_t)8  << 20)); //  4 MiB: [128][2048]
  float2* h0     = (float2*)(ws + ((size_t)12 << 20)); //  2 MiB: [128][2048]
  ushort* xb     = (ushort*)(ws + ((size_t)16 << 20)); // 32 MiB: x bf16 (alive thru ln_k)
  ushort* outb   = (ushort*)(ws + ((size_t)48 << 20)); // 32 MiB: scan out bf16
  ushort* linb   = (ushort*)(ws + ((size_t)80 << 20)); // 64 MiB: lin bf16
  ushort* yb     = (ushort*)(ws + ((size_t)80 << 20)); // 32 MiB: y bf16 (overlays dead linb)

  // weight prep
  tconv<<<dim3(512 / 32, 1024 / 32), dim3(32, 8), 0, stream>>>(Wt, 1024, 512, wcat_t, 0);
  tconv<<<dim3(512 / 32, 1024 / 32), dim3(32, 8), 0, stream>>>(Wr, 1024, 512, wcat_t, 512);
  tconv<<<dim3(1024 / 32, 1024 / 32), dim3(32, 8), 0, stream>>>(Wi, 1024, 1024, wcat_t, 1024);
  tconv<<<dim3(1024 / 32, 1024 / 32), dim3(32, 8), 0, stream>>>(Wo, 1024, 1024, wo_t, 0);
  pack_bias<<<8, 256, 0, stream>>>(bt, br, bi, bcat);
  xconv<<<16384, 256, 0, stream>>>((const float4*)x, xb, 4194304);

  // lin(bf16) = x @ [Wt|Wr|Wi] + [bt|br|bi]   (M=16384 N=2048 K=1024, 512 blocks)
  gemm256<256><<<512, 512, 0, stream>>>(xb, wcat_t, linb, bcat, 16384, 2048, 1024, 8);

  // chunked complex scan
  scan_k1<<<dim3(8, 128), 256, 0, stream>>>(linb, agg);
  scan_k2<<<8, 256, 0, stream>>>(agg, h0);
  scan_k3<<<dim3(8, 128), 256, 0, stream>>>(linb, h0, outb);

  // yb(bf16) = out @ Wo + bo   (M=16384 N=1024 K=1024, 512 blocks of 128x256)
  gemm256<128><<<512, 512, 0, stream>>>(outb, wo_t, yb, bo, 16384, 1024, 1024, 4);

  // layernorm(yb + xb) -> d_out
  ln_k<<<16384, 256, 0, stream>>>(yb, xb, gamma, beta, (float*)d_out);
}